// Round 1
// baseline (1529.066 us; speedup 1.0000x reference)
//
#include <hip/hip_runtime.h>
#include <math.h>

// Problem constants (reference: B=64, N=197, C=768, H=12, keep=0.7 -> 138)
#define BB   64
#define NTOK 197
#define CC   768
#define HH   12
#define DH   64
#define MTOT (BB * NTOK)          // 12608
#define LEFT 138

// d_out layout (floats, concatenated in return order)
#define XOUT_OFF  0
#define INDEX_OFF 9682944         // B*N*C
#define IDX_OFF   16465920        // + B*138*C
#define CLS_OFF   16474752        // + B*138
#define LT_OFF    16487296        // + B*196

__device__ __forceinline__ float bf2f(unsigned short u) {
    union { unsigned int i; float f; } x; x.i = ((unsigned int)u) << 16; return x.f;
}
__device__ __forceinline__ unsigned short f2bf(float f) {
    union { float f; unsigned int i; } x; x.f = f;
    unsigned int r = x.i + 0x7FFFu + ((x.i >> 16) & 1u);   // RNE
    return (unsigned short)(r >> 16);
}

// ---------------------------------------------------------------------------
// fp32 GEMM, 128x128 tile, 256 threads, 8x8 per thread, BK=16.
// mode 0: qkv — scatter columns into q/k/v [B,H,N,64] (+bias)
// mode 1: proj — write row-major [M, CC] (+bias)
// ---------------------------------------------------------------------------
__global__ __launch_bounds__(256)
void gemm128(const float* __restrict__ A, const float* __restrict__ W,
             const float* __restrict__ bias, int ncols, int mode,
             float* __restrict__ o0, float* __restrict__ o1, float* __restrict__ o2)
{
    const int m0 = blockIdx.x * 128;
    const int n0 = blockIdx.y * 128;
    const int tid = threadIdx.x;
    __shared__ __align__(16) float As[16 * 128];   // As[kk][m]
    __shared__ __align__(16) float Bs[16 * 128];   // Bs[kk][n]
    float acc[8][8];
#pragma unroll
    for (int i = 0; i < 8; ++i)
#pragma unroll
        for (int j = 0; j < 8; ++j) acc[i][j] = 0.f;
    const int tm = tid >> 4, tn = tid & 15;

    for (int k0 = 0; k0 < CC; k0 += 16) {
#pragma unroll
        for (int f = tid; f < 512; f += 256) {        // A tile 128x16
            int r  = f >> 2;
            int c4 = (f & 3) << 2;
            int m  = m0 + r;
            float4 a = make_float4(0.f, 0.f, 0.f, 0.f);
            if (m < MTOT) a = *(const float4*)(A + (size_t)m * CC + k0 + c4);
            As[(c4 + 0) * 128 + r] = a.x;
            As[(c4 + 1) * 128 + r] = a.y;
            As[(c4 + 2) * 128 + r] = a.z;
            As[(c4 + 3) * 128 + r] = a.w;
        }
#pragma unroll
        for (int f = tid; f < 512; f += 256) {        // B tile 16x128
            int r  = f >> 5;
            int c4 = (f & 31) << 2;
            *(float4*)&Bs[r * 128 + c4] =
                *(const float4*)(W + (size_t)(k0 + r) * ncols + n0 + c4);
        }
        __syncthreads();
#pragma unroll
        for (int kk = 0; kk < 16; ++kk) {
            float a_frag[8], b_frag[8];
            *(float4*)&a_frag[0] = *(const float4*)&As[kk * 128 + tm * 8];
            *(float4*)&a_frag[4] = *(const float4*)&As[kk * 128 + tm * 8 + 4];
            *(float4*)&b_frag[0] = *(const float4*)&Bs[kk * 128 + tn * 8];
            *(float4*)&b_frag[4] = *(const float4*)&Bs[kk * 128 + tn * 8 + 4];
#pragma unroll
            for (int i = 0; i < 8; ++i)
#pragma unroll
                for (int j = 0; j < 8; ++j)
                    acc[i][j] = fmaf(a_frag[i], b_frag[j], acc[i][j]);
        }
        __syncthreads();
    }

#pragma unroll
    for (int i = 0; i < 8; ++i) {
        int m = m0 + tm * 8 + i;
        if (m >= MTOT) continue;
        int b = m / NTOK, n = m - b * NTOK;
#pragma unroll
        for (int j = 0; j < 8; ++j) {
            int col = n0 + tn * 8 + j;
            float val = acc[i][j] + bias[col];
            if (mode == 1) {
                o0[(size_t)m * CC + col] = val;
            } else {
                int t   = col / CC;
                int rem = col - t * CC;
                int h   = rem >> 6;
                int dd  = rem & 63;
                float* dst = (t == 0) ? o0 : (t == 1 ? o1 : o2);
                dst[(((size_t)b * HH + h) * NTOK + n) * DH + dd] = val;
            }
        }
    }
}

// ---------------------------------------------------------------------------
// Bulk attention: one block per (b,h). K,V as bf16 in LDS (64KB budget),
// one row per wave, wave-shuffle softmax. Output -> attn_out [B,N,C].
// (Row-0 probabilities for pruning come from the exact fp32 kernel below;
//  this kernel's row 0 only feeds x_out, which tolerates bf16 noise.)
// ---------------------------------------------------------------------------
#define KS 68   // ushort row stride (pad: breaks power-of-2 bank stride)

__global__ __launch_bounds__(256)
void attn_bulk(const float* __restrict__ qws, const float* __restrict__ kws,
               const float* __restrict__ vws, float* __restrict__ attn_out)
{
    const int bh = blockIdx.x;            // 0..767
    const int b = bh / HH, h = bh - b * HH;
    const int tid  = threadIdx.x;
    const int wave = tid >> 6, lane = tid & 63;
    __shared__ __align__(16) unsigned short Kb[NTOK * KS];
    __shared__ __align__(16) unsigned short Vb[NTOK * KS];
    __shared__ __align__(16) float pbuf[4][NTOK + 3];
    __shared__ __align__(16) float qbuf[4][DH];

    const float* kg = kws + (size_t)bh * NTOK * DH;
    const float* vg = vws + (size_t)bh * NTOK * DH;
    for (int f = tid; f < NTOK * 16; f += 256) {
        int j = f >> 4, c4 = (f & 15) << 2;
        float4 kf = *(const float4*)(kg + j * DH + c4);
        float4 vf = *(const float4*)(vg + j * DH + c4);
        ushort4 k4; k4.x = f2bf(kf.x); k4.y = f2bf(kf.y); k4.z = f2bf(kf.z); k4.w = f2bf(kf.w);
        ushort4 v4; v4.x = f2bf(vf.x); v4.y = f2bf(vf.y); v4.z = f2bf(vf.z); v4.w = f2bf(vf.w);
        *(ushort4*)&Kb[j * KS + c4] = k4;
        *(ushort4*)&Vb[j * KS + c4] = v4;
    }
    __syncthreads();

    const float scale = 0.125f;           // 64^-0.5
    for (int i0 = 0; i0 < 200; i0 += 4) { // uniform trip count for barriers
        const int i = i0 + wave;
        const bool active = (i < NTOK);   // wave-uniform
        if (active) qbuf[wave][lane] = qws[((size_t)bh * NTOK + i) * DH + lane];
        __syncthreads();

        float pv[4];
        if (active) {
            float s[4];
            float mymax = -1e30f;
#pragma unroll
            for (int t = 0; t < 4; ++t) {
                int j = lane + 64 * t;
                s[t] = -1e30f;
                if (j < NTOK) {
                    float acc = 0.f;
#pragma unroll
                    for (int dd = 0; dd < DH; dd += 8) {
                        ushort4 ka = *(const ushort4*)&Kb[j * KS + dd];
                        ushort4 kb = *(const ushort4*)&Kb[j * KS + dd + 4];
                        float4  qa = *(const float4*)&qbuf[wave][dd];
                        float4  qb = *(const float4*)&qbuf[wave][dd + 4];
                        acc = fmaf(qa.x, bf2f(ka.x), acc);
                        acc = fmaf(qa.y, bf2f(ka.y), acc);
                        acc = fmaf(qa.z, bf2f(ka.z), acc);
                        acc = fmaf(qa.w, bf2f(ka.w), acc);
                        acc = fmaf(qb.x, bf2f(kb.x), acc);
                        acc = fmaf(qb.y, bf2f(kb.y), acc);
                        acc = fmaf(qb.z, bf2f(kb.z), acc);
                        acc = fmaf(qb.w, bf2f(kb.w), acc);
                    }
                    s[t] = acc * scale;
                    mymax = fmaxf(mymax, s[t]);
                }
            }
#pragma unroll
            for (int off = 32; off > 0; off >>= 1)
                mymax = fmaxf(mymax, __shfl_xor(mymax, off, 64));
            float mysum = 0.f;
#pragma unroll
            for (int t = 0; t < 4; ++t) {
                int j = lane + 64 * t;
                pv[t] = 0.f;
                if (j < NTOK) { pv[t] = __expf(s[t] - mymax); mysum += pv[t]; }
            }
#pragma unroll
            for (int off = 32; off > 0; off >>= 1)
                mysum += __shfl_xor(mysum, off, 64);
            float inv = 1.f / mysum;
#pragma unroll
            for (int t = 0; t < 4; ++t) {
                int j = lane + 64 * t;
                if (j < NTOK) pbuf[wave][j] = pv[t] * inv;
            }
        }
        __syncthreads();

        if (active) {
            float acc = 0.f;
            int j = 0;
            for (; j + 4 <= 196; j += 4) {
                float4 p4 = *(const float4*)&pbuf[wave][j];
                acc = fmaf(p4.x, bf2f(Vb[(j + 0) * KS + lane]), acc);
                acc = fmaf(p4.y, bf2f(Vb[(j + 1) * KS + lane]), acc);
                acc = fmaf(p4.z, bf2f(Vb[(j + 2) * KS + lane]), acc);
                acc = fmaf(p4.w, bf2f(Vb[(j + 3) * KS + lane]), acc);
            }
            for (; j < NTOK; ++j)
                acc = fmaf(pbuf[wave][j], bf2f(Vb[j * KS + lane]), acc);
            attn_out[((size_t)b * NTOK + i) * CC + h * DH + lane] = acc;
        }
    }
}

// ---------------------------------------------------------------------------
// Exact fp32 CLS-row softmax per (b,h): q0·K in fp32, full-precision softmax.
// Writes probs for tokens 1..196 to row0 ws — this feeds the top-k ORDER,
// which must match the fp32 numpy reference exactly.
// ---------------------------------------------------------------------------
__global__ __launch_bounds__(256)
void cls_exact(const float* __restrict__ qws, const float* __restrict__ kws,
               float* __restrict__ row0)
{
    const int bh = blockIdx.x;
    const int tid = threadIdx.x;
    __shared__ __align__(16) float q0[DH];
    __shared__ float red[256];

    if (tid < DH) q0[tid] = qws[(size_t)bh * NTOK * DH + tid];
    __syncthreads();

    float s = -1e30f;
    if (tid < NTOK) {
        const float* kg = kws + ((size_t)bh * NTOK + tid) * DH;
        float acc = 0.f;
#pragma unroll
        for (int dd = 0; dd < DH; dd += 4) {
            float4 kf = *(const float4*)(kg + dd);
            float4 qf = *(const float4*)&q0[dd];
            acc = fmaf(qf.x, kf.x, acc);
            acc = fmaf(qf.y, kf.y, acc);
            acc = fmaf(qf.z, kf.z, acc);
            acc = fmaf(qf.w, kf.w, acc);
        }
        s = acc * 0.125f;
    }
    red[tid] = s;
    __syncthreads();
    for (int st = 128; st > 0; st >>= 1) {
        if (tid < st) red[tid] = fmaxf(red[tid], red[tid + st]);
        __syncthreads();
    }
    float m = red[0];
    __syncthreads();
    float e = 0.f;
    if (tid < NTOK) e = expf(s - m);
    red[tid] = e;
    __syncthreads();
    for (int st = 128; st > 0; st >>= 1) {
        if (tid < st) red[tid] += red[tid + st];
        __syncthreads();
    }
    float denom = red[0];
    if (tid >= 1 && tid < NTOK)
        row0[(size_t)bh * (NTOK - 1) + tid - 1] = e / denom;
}

// ---------------------------------------------------------------------------
// Per-batch: cls_attn = mean over heads; bitonic top-k (exact jax.lax.top_k
// semantics: sort by (-value, index) lexicographic); write idx/index/cls/lt.
// ---------------------------------------------------------------------------
__global__ __launch_bounds__(256)
void topk_kernel(const float* __restrict__ row0, float* __restrict__ out, int write_lt)
{
    const int b = blockIdx.x;
    const int tid = threadIdx.x;
    __shared__ float vals[256];
    __shared__ int   idxs[256];

    float v = -INFINITY;
    int   id = 256 + tid;                  // unique padding indices
    if (tid < NTOK - 1) {
        float s = 0.f;
        for (int hh = 0; hh < HH; ++hh)
            s += row0[((size_t)b * HH + hh) * (NTOK - 1) + tid];
        v = s * (1.0f / 12.0f);
        id = tid;
        out[CLS_OFF + (size_t)b * (NTOK - 1) + tid] = v;
    }
    vals[tid] = v; idxs[tid] = id;
    __syncthreads();

    for (int k = 2; k <= 256; k <<= 1) {
        for (int j = k >> 1; j > 0; j >>= 1) {
            int ixj = tid ^ j;
            if (ixj > tid) {
                float va = vals[tid], vb = vals[ixj];
                int   ia = idxs[tid], ib = idxs[ixj];
                // aLess: a precedes b in final order (desc value, ties lower idx)
                bool aLess = (va > vb) || (va == vb && ia < ib);
                bool dir   = ((tid & k) == 0);
                if (dir != aLess) {
                    vals[tid] = vb; vals[ixj] = va;
                    idxs[tid] = ib; idxs[ixj] = ia;
                }
            }
            __syncthreads();
        }
    }

    if (tid < LEFT) out[IDX_OFF + (size_t)b * LEFT + tid] = (float)idxs[tid];
    for (int u = tid; u < LEFT * CC; u += 256) {
        int t = u / CC;
        out[INDEX_OFF + (size_t)b * LEFT * CC + u] = (float)idxs[t];
    }
    if (write_lt && b == 0 && tid == 0) out[LT_OFF] = (float)LEFT;
}

// ---------------------------------------------------------------------------
extern "C" void kernel_launch(void* const* d_in, const int* in_sizes, int n_in,
                              void* d_out, int out_size, void* d_ws, size_t ws_size,
                              hipStream_t stream)
{
    const float* x      = (const float*)d_in[0];
    const float* qkv_w  = (const float*)d_in[1];
    const float* qkv_b  = (const float*)d_in[2];
    const float* proj_w = (const float*)d_in[3];
    const float* proj_b = (const float*)d_in[4];
    float* out = (float*)d_out;

    // workspace layout (floats): q, k, v [B,H,N,64] + attn_out [B,N,C] + row0 [B*H,196]
    float* ws       = (float*)d_ws;
    float* qws      = ws;
    float* kws      = qws + (size_t)MTOT * CC;
    float* vws      = kws + (size_t)MTOT * CC;
    float* attn_out = vws + (size_t)MTOT * CC;
    float* row0     = attn_out + (size_t)MTOT * CC;
    // total: (4*9682944 + 768*196) * 4 B ≈ 148.3 MB

    gemm128<<<dim3(99, 18), 256, 0, stream>>>(x, qkv_w, qkv_b, 3 * CC, 0, qws, kws, vws);
    attn_bulk<<<dim3(BB * HH), 256, 0, stream>>>(qws, kws, vws, attn_out);
    cls_exact<<<dim3(BB * HH), 256, 0, stream>>>(qws, kws, row0);
    gemm128<<<dim3(99, 6), 256, 0, stream>>>(attn_out, proj_w, proj_b, CC, 1,
                                             out + XOUT_OFF, nullptr, nullptr);
    topk_kernel<<<dim3(BB), 256, 0, stream>>>(row0, out, (out_size > LT_OFF) ? 1 : 0);
}

// Round 2
// 503.202 us; speedup vs baseline: 3.0387x; 3.0387x over previous
//
#include <hip/hip_runtime.h>
#include <math.h>

#define BB   64
#define NTOK 197
#define CC   768
#define HH   12
#define DH   64
#define MTOT (BB * NTOK)          // 12608
#define MPAD 12672                // 99*128
#define LEFT 138

// d_out layout (floats, concatenated in return order)
#define XOUT_OFF  0
#define INDEX_OFF 9682944         // B*N*C
#define IDX_OFF   16465920        // + B*138*C
#define CLS_OFF   16474752        // + B*138
#define LT_OFF    16487296        // + B*196

typedef short s8v __attribute__((ext_vector_type(8)));
typedef float f4v __attribute__((ext_vector_type(4)));

__device__ __forceinline__ unsigned short f2bf(float f) {
    union { float f; unsigned int i; } x; x.f = f;
    unsigned int r = x.i + 0x7FFFu + ((x.i >> 16) & 1u);   // RNE
    return (unsigned short)(r >> 16);
}

// ---------------------------------------------------------------------------
// fp32 [M,768] -> bf16 [M,768] (rows < MTOT; pad rows stay poison = tiny)
// ---------------------------------------------------------------------------
__global__ __launch_bounds__(256)
void convert_x(const float* __restrict__ in, unsigned short* __restrict__ outb)
{
    size_t i = ((size_t)blockIdx.x * 256 + threadIdx.x) * 8;   // grid sized exactly
    float4 a = *(const float4*)(in + i);
    float4 b = *(const float4*)(in + i + 4);
    s8v r;
    r[0] = (short)f2bf(a.x); r[1] = (short)f2bf(a.y);
    r[2] = (short)f2bf(a.z); r[3] = (short)f2bf(a.w);
    r[4] = (short)f2bf(b.x); r[5] = (short)f2bf(b.y);
    r[6] = (short)f2bf(b.z); r[7] = (short)f2bf(b.w);
    *(s8v*)(outb + i) = r;
}

// ---------------------------------------------------------------------------
// fp32 W [768,N] -> bf16 W^T [N,768]
// ---------------------------------------------------------------------------
__global__ __launch_bounds__(256)
void transpose_w(const float* __restrict__ in, unsigned short* __restrict__ outb, int N)
{
    __shared__ float tile[32][33];
    const int bi = blockIdx.x, bj = blockIdx.y;   // bi over K(=768)/32, bj over N/32
    const int tx = threadIdx.x & 31, ty = threadIdx.x >> 5;  // ty 0..7
#pragma unroll
    for (int r = ty; r < 32; r += 8)
        tile[r][tx] = in[(size_t)(bi * 32 + r) * N + bj * 32 + tx];
    __syncthreads();
#pragma unroll
    for (int r = ty; r < 32; r += 8)
        outb[(size_t)(bj * 32 + r) * 768 + bi * 32 + tx] = f2bf(tile[tx][r]);
}

// ---------------------------------------------------------------------------
// bf16 MFMA GEMM: A [MPAD,768] bf16 row-major, BT [N,768] bf16 (W transposed).
// 128x128 tile, 4 waves, each wave 64x64 via 4x4 16x16x32 mfma tiles.
// mode 0: qkv -> scatter bf16 to q/k/v [B,H,N,64] (+bias)
// mode 1: proj -> fp32 out [M,768] (+bias)
// ---------------------------------------------------------------------------
#define LSTR 72   // LDS row stride in shorts (64 + 8 pad; 144B = 9*16B)

__global__ __launch_bounds__(256)
void gemm_bf16(const unsigned short* __restrict__ A, const unsigned short* __restrict__ BT,
               const float* __restrict__ bias, int mode,
               unsigned short* __restrict__ qb, unsigned short* __restrict__ kb,
               unsigned short* __restrict__ vb, float* __restrict__ outf)
{
    const int m0 = blockIdx.x * 128;
    const int n0 = blockIdx.y * 128;
    const int tid = threadIdx.x;
    const int wave = tid >> 6, lane = tid & 63;
    const int quad = lane >> 4, l16 = lane & 15;
    const int rowbase = (wave >> 1) * 64, colbase = (wave & 1) * 64;
    __shared__ short As[128 * LSTR];
    __shared__ short Bs[128 * LSTR];

    f4v acc[4][4];
#pragma unroll
    for (int i = 0; i < 4; ++i)
#pragma unroll
        for (int j = 0; j < 4; ++j) acc[i][j] = (f4v)0.f;

    for (int k0 = 0; k0 < 768; k0 += 64) {
#pragma unroll
        for (int f = tid; f < 1024; f += 256) {
            int r = f >> 3, off = (f & 7) << 3;
            *(s8v*)&As[r * LSTR + off] = *(const s8v*)(A  + (size_t)(m0 + r) * 768 + k0 + off);
            *(s8v*)&Bs[r * LSTR + off] = *(const s8v*)(BT + (size_t)(n0 + r) * 768 + k0 + off);
        }
        __syncthreads();
#pragma unroll
        for (int ks = 0; ks < 2; ++ks) {
            const int ko = ks * 32 + quad * 8;
            s8v af[4], bf[4];
#pragma unroll
            for (int i = 0; i < 4; ++i)
                af[i] = *(const s8v*)&As[(rowbase + i * 16 + l16) * LSTR + ko];
#pragma unroll
            for (int j = 0; j < 4; ++j)
                bf[j] = *(const s8v*)&Bs[(colbase + j * 16 + l16) * LSTR + ko];
#pragma unroll
            for (int i = 0; i < 4; ++i)
#pragma unroll
                for (int j = 0; j < 4; ++j)
                    acc[i][j] = __builtin_amdgcn_mfma_f32_16x16x32_bf16(af[i], bf[j], acc[i][j], 0, 0, 0);
        }
        __syncthreads();
    }

#pragma unroll
    for (int i = 0; i < 4; ++i) {
#pragma unroll
        for (int j = 0; j < 4; ++j) {
            const int gcolb = n0 + colbase + j * 16;      // 16-aligned tile col base
            const float bv = bias[gcolb + l16];
            if (mode == 1) {
#pragma unroll
                for (int reg = 0; reg < 4; ++reg) {
                    int row = m0 + rowbase + i * 16 + quad * 4 + reg;
                    if (row < MTOT)
                        outf[(size_t)row * 768 + gcolb + l16] = acc[i][j][reg] + bv;
                }
            } else {
                int t = gcolb / 768;
                int rem = gcolb - t * 768;
                int h = rem >> 6, dd = (rem & 63) + l16;
                unsigned short* dst = (t == 0) ? qb : (t == 1 ? kb : vb);
#pragma unroll
                for (int reg = 0; reg < 4; ++reg) {
                    int row = m0 + rowbase + i * 16 + quad * 4 + reg;
                    if (row < MTOT) {
                        int b = row / NTOK, n = row - b * NTOK;
                        dst[(((size_t)b * HH + h) * NTOK + n) * DH + dd] = f2bf(acc[i][j][reg] + bv);
                    }
                }
            }
        }
    }
}

// ---------------------------------------------------------------------------
// MFMA attention per (b,h). 4 waves; each wave owns 16-row strips (13 strips).
// QK^T: A=Q frags from global, B=K frags from global (L1/L2-resident).
// P -> per-wave LDS strip (bf16, unnormalized); PV: B=V^T in LDS. O scaled
// by 1/rowsum at store. Pads: cols>=197 forced to p=0; V^T pad toks zeroed.
// ---------------------------------------------------------------------------
#define PSTR 232   // shorts (464B = 29*16B); 2-way bank alias only

__global__ __launch_bounds__(256)
void attn_mfma(const unsigned short* __restrict__ qbf, const unsigned short* __restrict__ kbf,
               const unsigned short* __restrict__ vbf, unsigned short* __restrict__ attnbf)
{
    const int bh = blockIdx.x;
    const int b = bh / HH, h = bh - b * HH;
    const int tid = threadIdx.x;
    const int wave = tid >> 6, lane = tid & 63;
    const int quad = lane >> 4, l16 = lane & 15;
    __shared__ short Vs[64 * PSTR];        // Vs[dd][tok] (V transposed)
    __shared__ short Ps[4][16 * PSTR];     // per-wave P strip [row][tok]

    const unsigned short* qg = qbf + (size_t)bh * NTOK * DH;
    const unsigned short* kg = kbf + (size_t)bh * NTOK * DH;
    const unsigned short* vg = vbf + (size_t)bh * NTOK * DH;

    if (tid < NTOK) {
#pragma unroll
        for (int c = 0; c < 8; ++c) {
            s8v vv = *(const s8v*)(vg + tid * DH + c * 8);
#pragma unroll
            for (int e = 0; e < 8; ++e) Vs[(c * 8 + e) * PSTR + tid] = vv[e];
        }
    }
    for (int f = tid; f < 64 * (PSTR - NTOK); f += 256) {   // zero pad toks 197..231
        int dd = f / (PSTR - NTOK);
        int tk = NTOK + (f - dd * (PSTR - NTOK));
        Vs[dd * PSTR + tk] = 0;
    }
    __syncthreads();

    for (int strip = wave; strip < 13; strip += 4) {
        const int mq = min(strip * 16 + l16, NTOK - 1);
        const s8v aq0 = *(const s8v*)(qg + mq * DH + quad * 8);
        const s8v aq1 = *(const s8v*)(qg + mq * DH + 32 + quad * 8);

        f4v sacc[14];
#pragma unroll
        for (int j = 0; j < 14; ++j) sacc[j] = (f4v)0.f;
#pragma unroll
        for (int j = 0; j < 14; ++j) {
            const int kt = min(j * 16 + l16, NTOK - 1);
            s8v bk0 = *(const s8v*)(kg + kt * DH + quad * 8);
            s8v bk1 = *(const s8v*)(kg + kt * DH + 32 + quad * 8);
            sacc[j] = __builtin_amdgcn_mfma_f32_16x16x32_bf16(aq0, bk0, sacc[j], 0, 0, 0);
            sacc[j] = __builtin_amdgcn_mfma_f32_16x16x32_bf16(aq1, bk1, sacc[j], 0, 0, 0);
        }

        // softmax over cols (row = quad*4+reg, col = j*16+l16)
        float m4[4] = {-1e30f, -1e30f, -1e30f, -1e30f};
#pragma unroll
        for (int j = 0; j < 14; ++j) {
            const bool valid = (j * 16 + l16) < NTOK;
#pragma unroll
            for (int r = 0; r < 4; ++r) {
                float s = valid ? sacc[j][r] * 0.125f : -1e30f;
                sacc[j][r] = s;
                m4[r] = fmaxf(m4[r], s);
            }
        }
#pragma unroll
        for (int off = 1; off < 16; off <<= 1)
#pragma unroll
            for (int r = 0; r < 4; ++r)
                m4[r] = fmaxf(m4[r], __shfl_xor(m4[r], off, 16));

        float sum4[4] = {0.f, 0.f, 0.f, 0.f};
#pragma unroll
        for (int j = 0; j < 14; ++j)
#pragma unroll
            for (int r = 0; r < 4; ++r) {
                float p = __expf(sacc[j][r] - m4[r]);   // masked cols -> 0
                sum4[r] += p;
                Ps[wave][(quad * 4 + r) * PSTR + j * 16 + l16] = (short)f2bf(p);
            }
#pragma unroll
        for (int off = 1; off < 16; off <<= 1)
#pragma unroll
            for (int r = 0; r < 4; ++r)
                sum4[r] += __shfl_xor(sum4[r], off, 16);

        // PV: O[16,64] += P[16,224] * V[224,64]
        f4v oacc[4];
#pragma unroll
        for (int j = 0; j < 4; ++j) oacc[j] = (f4v)0.f;
#pragma unroll
        for (int t = 0; t < 7; ++t) {
            const int ko = t * 32 + quad * 8;
            s8v ap = *(const s8v*)&Ps[wave][l16 * PSTR + ko];
#pragma unroll
            for (int j = 0; j < 4; ++j) {
                s8v bv = *(const s8v*)&Vs[(j * 16 + l16) * PSTR + ko];
                oacc[j] = __builtin_amdgcn_mfma_f32_16x16x32_bf16(ap, bv, oacc[j], 0, 0, 0);
            }
        }
        float rcp4[4];
#pragma unroll
        for (int r = 0; r < 4; ++r) rcp4[r] = 1.f / sum4[r];
#pragma unroll
        for (int j = 0; j < 4; ++j)
#pragma unroll
            for (int r = 0; r < 4; ++r) {
                int row = strip * 16 + quad * 4 + r;
                if (row < NTOK)
                    attnbf[((size_t)b * NTOK + row) * CC + h * DH + j * 16 + l16] =
                        f2bf(oacc[j][r] * rcp4[r]);
            }
    }
}

// ---------------------------------------------------------------------------
// Exact fp32 cls path (reassociated): q0[b,:]=x[b,0,:]@Wq+bq
// ---------------------------------------------------------------------------
__global__ __launch_bounds__(256)
void q0_kernel(const float* __restrict__ x, const float* __restrict__ qkv_w,
               const float* __restrict__ qkv_b, float* __restrict__ q0ws)
{
    const int b = blockIdx.x, tid = threadIdx.x;
    __shared__ float x0[CC];
    for (int c = tid; c < CC; c += 256) x0[c] = x[(size_t)b * NTOK * CC + c];
    __syncthreads();
    for (int o = tid; o < CC; o += 256) {
        float acc = qkv_b[o];
        for (int c = 0; c < CC; ++c)
            acc = fmaf(x0[c], qkv_w[(size_t)c * (3 * CC) + o], acc);
        q0ws[b * CC + o] = acc;
    }
}

// r[b,h,c] = sum_d Wk[c, h*64+d] * q0_h[d];  bconst[b,h] = q0_h . bk_h
__global__ __launch_bounds__(256)
void r_kernel(const float* __restrict__ qkv_w, const float* __restrict__ qkv_b,
              const float* __restrict__ q0ws, float* __restrict__ rws,
              float* __restrict__ bconst)
{
    const int blk = blockIdx.x;
    const int b = blk / HH, h = blk - b * HH;
    const int tid = threadIdx.x;
    __shared__ float q0h[DH];
    if (tid < DH) q0h[tid] = q0ws[b * CC + h * DH + tid];
    __syncthreads();
    for (int c = tid; c < CC; c += 256) {
        const float* wrow = qkv_w + (size_t)c * (3 * CC) + CC + h * DH;
        float acc = 0.f;
#pragma unroll
        for (int d = 0; d < DH; d += 4) {
            float4 w4 = *(const float4*)(wrow + d);
            acc = fmaf(w4.x, q0h[d + 0], acc);
            acc = fmaf(w4.y, q0h[d + 1], acc);
            acc = fmaf(w4.z, q0h[d + 2], acc);
            acc = fmaf(w4.w, q0h[d + 3], acc);
        }
        rws[((size_t)b * HH + h) * CC + c] = acc;
    }
    if (tid == 0) {
        float acc = 0.f;
        for (int d = 0; d < DH; ++d) acc += q0h[d] * qkv_b[CC + h * DH + d];
        bconst[blk] = acc;
    }
}

// per b: s[j,h] = x[b,j,:].r[b,h,:]*scale (+bconst); softmax_j per h; mean_h;
// bitonic top-k (exact (-val, idx) lexicographic); write cls/idx/index/lt.
__global__ __launch_bounds__(256)
void cls_topk(const float* __restrict__ x, const float* __restrict__ rws,
              const float* __restrict__ bconst, float* __restrict__ out, int write_lt)
{
    const int b = blockIdx.x, tid = threadIdx.x;
    const int wave = tid >> 6, lane = tid & 63;
    __shared__ float rs[CC * HH];        // rs[c*12+h]
    __shared__ float sbuf[HH][208];
    __shared__ float pm[4][208];
    __shared__ float bc[HH];
    __shared__ float vals[256];
    __shared__ int   idxs[256];

    for (int f = tid; f < CC * HH; f += 256) {
        int h = f / CC, c = f - h * CC;
        rs[c * HH + h] = rws[((size_t)b * HH + h) * CC + c];
    }
    if (tid < HH) bc[tid] = bconst[b * HH + tid];
    for (int jj = lane; jj < 208; jj += 64) pm[wave][jj] = 0.f;
    __syncthreads();

    if (tid < NTOK) {
        float a12[HH];
#pragma unroll
        for (int h = 0; h < HH; ++h) a12[h] = 0.f;
        const float* xr = x + ((size_t)b * NTOK + tid) * CC;
        for (int c = 0; c < CC; ++c) {
            float xv = xr[c];
#pragma unroll
            for (int h = 0; h < HH; ++h) a12[h] = fmaf(xv, rs[c * HH + h], a12[h]);
        }
#pragma unroll
        for (int h = 0; h < HH; ++h) sbuf[h][tid] = (a12[h] + bc[h]) * 0.125f;
    }
    __syncthreads();

    for (int h = wave; h < HH; h += 4) {
        float sv[4], ev[4];
        float mx = -1e30f;
#pragma unroll
        for (int t = 0; t < 4; ++t) {
            int j = lane + 64 * t;
            sv[t] = (j < NTOK) ? sbuf[h][j] : -1e30f;
            mx = fmaxf(mx, sv[t]);
        }
#pragma unroll
        for (int off = 1; off < 64; off <<= 1) mx = fmaxf(mx, __shfl_xor(mx, off, 64));
        float sm = 0.f;
#pragma unroll
        for (int t = 0; t < 4; ++t) {
            int j = lane + 64 * t;
            ev[t] = (j < NTOK) ? expf(sv[t] - mx) : 0.f;
            sm += ev[t];
        }
#pragma unroll
        for (int off = 1; off < 64; off <<= 1) sm += __shfl_xor(sm, off, 64);
#pragma unroll
        for (int t = 0; t < 4; ++t) {
            int j = lane + 64 * t;
            if (j < NTOK) pm[wave][j] += ev[t] / sm;
        }
    }
    __syncthreads();

    float v = -INFINITY;
    int id = 256 + tid;
    if (tid < NTOK - 1) {
        int j = tid + 1;
        float s = ((pm[0][j] + pm[1][j]) + (pm[2][j] + pm[3][j])) * (1.f / 12.f);
        v = s; id = tid;
        out[CLS_OFF + (size_t)b * (NTOK - 1) + tid] = s;
    }
    vals[tid] = v; idxs[tid] = id;
    __syncthreads();

    for (int k = 2; k <= 256; k <<= 1) {
        for (int j = k >> 1; j > 0; j >>= 1) {
            int ixj = tid ^ j;
            if (ixj > tid) {
                float va = vals[tid], vb2 = vals[ixj];
                int ia = idxs[tid], ib = idxs[ixj];
                bool aLess = (va > vb2) || (va == vb2 && ia < ib);
                bool dir = ((tid & k) == 0);
                if (dir != aLess) {
                    vals[tid] = vb2; vals[ixj] = va;
                    idxs[tid] = ib;  idxs[ixj] = ia;
                }
            }
            __syncthreads();
        }
    }

    if (tid < LEFT) out[IDX_OFF + (size_t)b * LEFT + tid] = (float)idxs[tid];
    for (int u = tid; u < LEFT * CC; u += 256) {
        int t = u / CC;
        out[INDEX_OFF + (size_t)b * LEFT * CC + u] = (float)idxs[t];
    }
    if (write_lt && b == 0 && tid == 0) out[LT_OFF] = (float)LEFT;
}

// ---------------------------------------------------------------------------
extern "C" void kernel_launch(void* const* d_in, const int* in_sizes, int n_in,
                              void* d_out, int out_size, void* d_ws, size_t ws_size,
                              hipStream_t stream)
{
    const float* x      = (const float*)d_in[0];
    const float* qkv_w  = (const float*)d_in[1];
    const float* qkv_b  = (const float*)d_in[2];
    const float* proj_w = (const float*)d_in[3];
    const float* proj_b = (const float*)d_in[4];
    float* out = (float*)d_out;

    char* w = (char*)d_ws;
    unsigned short* xbf  = (unsigned short*)w; w += (size_t)MPAD * CC * 2;
    unsigned short* wt1  = (unsigned short*)w; w += (size_t)3 * CC * CC * 2;
    unsigned short* wt2  = (unsigned short*)w; w += (size_t)CC * CC * 2;
    unsigned short* qbf  = (unsigned short*)w; w += (size_t)BB * HH * NTOK * DH * 2;
    unsigned short* kbf  = (unsigned short*)w; w += (size_t)BB * HH * NTOK * DH * 2;
    unsigned short* vbf  = (unsigned short*)w; w += (size_t)BB * HH * NTOK * DH * 2;
    unsigned short* atbf = (unsigned short*)w; w += (size_t)MPAD * CC * 2;
    float* q0ws   = (float*)w; w += (size_t)BB * CC * 4;
    float* rws    = (float*)w; w += (size_t)BB * HH * CC * 4;
    float* bconst = (float*)w; w += (size_t)BB * HH * 4;
    // total ~104 MB

    convert_x<<<dim3(4728), 256, 0, stream>>>(x, xbf);                    // 12608*768 = 4728*2048
    transpose_w<<<dim3(24, 72), 256, 0, stream>>>(qkv_w, wt1, 3 * CC);
    transpose_w<<<dim3(24, 24), 256, 0, stream>>>(proj_w, wt2, CC);
    gemm_bf16<<<dim3(99, 18), 256, 0, stream>>>(xbf, wt1, qkv_b, 0, qbf, kbf, vbf, nullptr);
    attn_mfma<<<dim3(BB * HH), 256, 0, stream>>>(qbf, kbf, vbf, atbf);
    gemm_bf16<<<dim3(99, 6), 256, 0, stream>>>(atbf, wt2, proj_b, 1,
                                               nullptr, nullptr, nullptr, out + XOUT_OFF);
    q0_kernel<<<dim3(BB), 256, 0, stream>>>(x, qkv_w, qkv_b, q0ws);
    r_kernel<<<dim3(BB * HH), 256, 0, stream>>>(qkv_w, qkv_b, q0ws, rws, bconst);
    cls_topk<<<dim3(BB), 256, 0, stream>>>(x, rws, bconst, out, (out_size > LT_OFF) ? 1 : 0);
}

// Round 3
// 426.575 us; speedup vs baseline: 3.5845x; 1.1796x over previous
//
#include <hip/hip_runtime.h>
#include <math.h>

#define BB   64
#define NTOK 197
#define CC   768
#define HH   12
#define DH   64
#define MTOT (BB * NTOK)          // 12608
#define MPAD 12672                // 99*128
#define LEFT 138

// d_out layout (floats, concatenated in return order)
#define XOUT_OFF  0
#define INDEX_OFF 9682944         // B*N*C
#define IDX_OFF   16465920        // + B*138*C
#define CLS_OFF   16474752        // + B*138
#define LT_OFF    16487296        // + B*196

typedef short s8v __attribute__((ext_vector_type(8)));
typedef float f4v __attribute__((ext_vector_type(4)));

#define GLOAD16(g, l) __builtin_amdgcn_global_load_lds( \
    (const __attribute__((address_space(1))) unsigned int*)(g), \
    (__attribute__((address_space(3))) unsigned int*)(l), 16, 0, 0)

__device__ __forceinline__ unsigned short f2bf(float f) {
    union { float f; unsigned int i; } x; x.f = f;
    unsigned int r = x.i + 0x7FFFu + ((x.i >> 16) & 1u);   // RNE
    return (unsigned short)(r >> 16);
}

// ---------------------------------------------------------------------------
// fp32 [M,768] -> bf16 [M,768]
// ---------------------------------------------------------------------------
__global__ __launch_bounds__(256)
void convert_x(const float* __restrict__ in, unsigned short* __restrict__ outb)
{
    size_t i = ((size_t)blockIdx.x * 256 + threadIdx.x) * 8;
    float4 a = *(const float4*)(in + i);
    float4 b = *(const float4*)(in + i + 4);
    s8v r;
    r[0] = (short)f2bf(a.x); r[1] = (short)f2bf(a.y);
    r[2] = (short)f2bf(a.z); r[3] = (short)f2bf(a.w);
    r[4] = (short)f2bf(b.x); r[5] = (short)f2bf(b.y);
    r[6] = (short)f2bf(b.z); r[7] = (short)f2bf(b.w);
    *(s8v*)(outb + i) = r;
}

// ---------------------------------------------------------------------------
// fp32 W [768,N] -> bf16 W^T [N,768]
// ---------------------------------------------------------------------------
__global__ __launch_bounds__(256)
void transpose_w(const float* __restrict__ in, unsigned short* __restrict__ outb, int N)
{
    __shared__ float tile[32][33];
    const int bi = blockIdx.x, bj = blockIdx.y;
    const int tx = threadIdx.x & 31, ty = threadIdx.x >> 5;
#pragma unroll
    for (int r = ty; r < 32; r += 8)
        tile[r][tx] = in[(size_t)(bi * 32 + r) * N + bj * 32 + tx];
    __syncthreads();
#pragma unroll
    for (int r = ty; r < 32; r += 8)
        outb[(size_t)(bj * 32 + r) * 768 + bi * 32 + tx] = f2bf(tile[tx][r]);
}

// ---------------------------------------------------------------------------
// bf16 MFMA GEMM, m97-style: global_load_lds(16B) staging into XOR-swizzled
// unpadded LDS; 128x128 tile, BK=64, 4 waves, 4x4 16x16x32 mfma per wave.
// Grid is 1D: id -> (xcd = id&7, colTile = t%ncolt, rowTile = (t/ncolt)*8+xcd)
// so each XCD owns a row band across all column tiles (L2 locality).
// mode 0: qkv -> scatter bf16 q/k/v [B,H,N,64] (+bias); mode 1: fp32 out.
// ---------------------------------------------------------------------------
__global__ __launch_bounds__(256)
void gemm_bf16(const unsigned short* __restrict__ A, const unsigned short* __restrict__ BT,
               const float* __restrict__ bias, int ncolt, int mode,
               unsigned short* __restrict__ qb, unsigned short* __restrict__ kb,
               unsigned short* __restrict__ vb, float* __restrict__ outf)
{
    const int id = blockIdx.x;
    const int xcd = id & 7;
    const int t = id >> 3;
    const int ct = t % ncolt, s = t / ncolt;
    const int rt = s * 8 + xcd;
    if (rt >= 99) return;
    const int m0 = rt * 128, n0 = ct * 128;

    const int tid = threadIdx.x;
    const int wave = tid >> 6, lane = tid & 63;
    const int quad = lane >> 4, l16 = lane & 15;
    const int rowbase = (wave >> 1) * 64, colbase = (wave & 1) * 64;
    __shared__ __align__(16) short As[128 * 64];
    __shared__ __align__(16) short Bs[128 * 64];

    // staging: chunk c covers rows c*8..c*8+7 (128B each); lane l writes LDS
    // offset c*1024 + l*16; global source col-chunk is XOR-swizzled by row.
    const int rA   = lane >> 3;                    // row within chunk
    const int gcol = ((lane & 7) ^ rA) * 8;        // swizzled col (shorts)
    const unsigned short* gA[4];
    const unsigned short* gB[4];
#pragma unroll
    for (int i = 0; i < 4; ++i) {
        int c = wave * 4 + i;
        gA[i] = A  + (size_t)(m0 + c * 8 + rA) * 768 + gcol;
        gB[i] = BT + (size_t)(n0 + c * 8 + rA) * 768 + gcol;
    }
    // fragment read offsets (shorts); logical chunk q of row r at q^(r&7)
    int aoff[4], boff[4];
#pragma unroll
    for (int i = 0; i < 4; ++i) {
        aoff[i] = (rowbase + i * 16 + l16) * 64 + ((quad ^ (l16 & 7)) * 8);
        boff[i] = (colbase + i * 16 + l16) * 64 + ((quad ^ (l16 & 7)) * 8);
    }

    f4v acc[4][4];
#pragma unroll
    for (int i = 0; i < 4; ++i)
#pragma unroll
        for (int j = 0; j < 4; ++j) acc[i][j] = (f4v)0.f;

    for (int k0 = 0; k0 < 768; k0 += 64) {
#pragma unroll
        for (int i = 0; i < 4; ++i) {
            int c = wave * 4 + i;
            GLOAD16(gA[i] + k0, &As[c * 512]);
            GLOAD16(gB[i] + k0, &Bs[c * 512]);
        }
        __syncthreads();
#pragma unroll
        for (int ks = 0; ks < 2; ++ks) {
            const int x = ks * 32;     // ks=1 toggles bit 5 (chunk^4)
            s8v af[4], bf[4];
#pragma unroll
            for (int i = 0; i < 4; ++i) af[i] = *(const s8v*)&As[aoff[i] ^ x];
#pragma unroll
            for (int j = 0; j < 4; ++j) bf[j] = *(const s8v*)&Bs[boff[j] ^ x];
#pragma unroll
            for (int i = 0; i < 4; ++i)
#pragma unroll
                for (int j = 0; j < 4; ++j)
                    acc[i][j] = __builtin_amdgcn_mfma_f32_16x16x32_bf16(af[i], bf[j], acc[i][j], 0, 0, 0);
        }
        __syncthreads();
    }

#pragma unroll
    for (int i = 0; i < 4; ++i) {
#pragma unroll
        for (int j = 0; j < 4; ++j) {
            const int gcolb = n0 + colbase + j * 16;
            const float bv = bias[gcolb + l16];
            if (mode == 1) {
#pragma unroll
                for (int reg = 0; reg < 4; ++reg) {
                    int row = m0 + rowbase + i * 16 + quad * 4 + reg;
                    if (row < MTOT)
                        outf[(size_t)row * 768 + gcolb + l16] = acc[i][j][reg] + bv;
                }
            } else {
                int tt = gcolb / 768;
                int rem = gcolb - tt * 768;
                int h = rem >> 6, dd = (rem & 63) + l16;
                unsigned short* dst = (tt == 0) ? qb : (tt == 1 ? kb : vb);
#pragma unroll
                for (int reg = 0; reg < 4; ++reg) {
                    int row = m0 + rowbase + i * 16 + quad * 4 + reg;
                    if (row < MTOT) {
                        int b = row / NTOK, n = row - b * NTOK;
                        dst[(((size_t)b * HH + h) * NTOK + n) * DH + dd] = f2bf(acc[i][j][reg] + bv);
                    }
                }
            }
        }
    }
}

// ---------------------------------------------------------------------------
// MFMA attention per (b,h) — unchanged from round 2 (not top-5).
// ---------------------------------------------------------------------------
#define PSTR 232

__global__ __launch_bounds__(256)
void attn_mfma(const unsigned short* __restrict__ qbf, const unsigned short* __restrict__ kbf,
               const unsigned short* __restrict__ vbf, unsigned short* __restrict__ attnbf)
{
    const int bh = blockIdx.x;
    const int b = bh / HH, h = bh - b * HH;
    const int tid = threadIdx.x;
    const int wave = tid >> 6, lane = tid & 63;
    const int quad = lane >> 4, l16 = lane & 15;
    __shared__ short Vs[64 * PSTR];
    __shared__ short Ps[4][16 * PSTR];

    const unsigned short* qg = qbf + (size_t)bh * NTOK * DH;
    const unsigned short* kg = kbf + (size_t)bh * NTOK * DH;
    const unsigned short* vg = vbf + (size_t)bh * NTOK * DH;

    if (tid < NTOK) {
#pragma unroll
        for (int c = 0; c < 8; ++c) {
            s8v vv = *(const s8v*)(vg + tid * DH + c * 8);
#pragma unroll
            for (int e = 0; e < 8; ++e) Vs[(c * 8 + e) * PSTR + tid] = vv[e];
        }
    }
    for (int f = tid; f < 64 * (PSTR - NTOK); f += 256) {
        int dd = f / (PSTR - NTOK);
        int tk = NTOK + (f - dd * (PSTR - NTOK));
        Vs[dd * PSTR + tk] = 0;
    }
    __syncthreads();

    for (int strip = wave; strip < 13; strip += 4) {
        const int mq = min(strip * 16 + l16, NTOK - 1);
        const s8v aq0 = *(const s8v*)(qg + mq * DH + quad * 8);
        const s8v aq1 = *(const s8v*)(qg + mq * DH + 32 + quad * 8);

        f4v sacc[14];
#pragma unroll
        for (int j = 0; j < 14; ++j) sacc[j] = (f4v)0.f;
#pragma unroll
        for (int j = 0; j < 14; ++j) {
            const int kt = min(j * 16 + l16, NTOK - 1);
            s8v bk0 = *(const s8v*)(kg + kt * DH + quad * 8);
            s8v bk1 = *(const s8v*)(kg + kt * DH + 32 + quad * 8);
            sacc[j] = __builtin_amdgcn_mfma_f32_16x16x32_bf16(aq0, bk0, sacc[j], 0, 0, 0);
            sacc[j] = __builtin_amdgcn_mfma_f32_16x16x32_bf16(aq1, bk1, sacc[j], 0, 0, 0);
        }

        float m4[4] = {-1e30f, -1e30f, -1e30f, -1e30f};
#pragma unroll
        for (int j = 0; j < 14; ++j) {
            const bool valid = (j * 16 + l16) < NTOK;
#pragma unroll
            for (int r = 0; r < 4; ++r) {
                float s = valid ? sacc[j][r] * 0.125f : -1e30f;
                sacc[j][r] = s;
                m4[r] = fmaxf(m4[r], s);
            }
        }
#pragma unroll
        for (int off = 1; off < 16; off <<= 1)
#pragma unroll
            for (int r = 0; r < 4; ++r)
                m4[r] = fmaxf(m4[r], __shfl_xor(m4[r], off, 16));

        float sum4[4] = {0.f, 0.f, 0.f, 0.f};
#pragma unroll
        for (int j = 0; j < 14; ++j)
#pragma unroll
            for (int r = 0; r < 4; ++r) {
                float p = __expf(sacc[j][r] - m4[r]);
                sum4[r] += p;
                Ps[wave][(quad * 4 + r) * PSTR + j * 16 + l16] = (short)f2bf(p);
            }
#pragma unroll
        for (int off = 1; off < 16; off <<= 1)
#pragma unroll
            for (int r = 0; r < 4; ++r)
                sum4[r] += __shfl_xor(sum4[r], off, 16);

        f4v oacc[4];
#pragma unroll
        for (int j = 0; j < 4; ++j) oacc[j] = (f4v)0.f;
#pragma unroll
        for (int t = 0; t < 7; ++t) {
            const int ko = t * 32 + quad * 8;
            s8v ap = *(const s8v*)&Ps[wave][l16 * PSTR + ko];
#pragma unroll
            for (int j = 0; j < 4; ++j) {
                s8v bv = *(const s8v*)&Vs[(j * 16 + l16) * PSTR + ko];
                oacc[j] = __builtin_amdgcn_mfma_f32_16x16x32_bf16(ap, bv, oacc[j], 0, 0, 0);
            }
        }
        float rcp4[4];
#pragma unroll
        for (int r = 0; r < 4; ++r) rcp4[r] = 1.f / sum4[r];
#pragma unroll
        for (int j = 0; j < 4; ++j)
#pragma unroll
            for (int r = 0; r < 4; ++r) {
                int row = strip * 16 + quad * 4 + r;
                if (row < NTOK)
                    attnbf[((size_t)b * NTOK + row) * CC + h * DH + j * 16 + l16] =
                        f2bf(oacc[j][r] * rcp4[r]);
            }
    }
}

// ---------------------------------------------------------------------------
// Exact fp32 cls path (reassociated) — unchanged.
// ---------------------------------------------------------------------------
__global__ __launch_bounds__(256)
void q0_kernel(const float* __restrict__ x, const float* __restrict__ qkv_w,
               const float* __restrict__ qkv_b, float* __restrict__ q0ws)
{
    const int b = blockIdx.x, tid = threadIdx.x;
    __shared__ float x0[CC];
    for (int c = tid; c < CC; c += 256) x0[c] = x[(size_t)b * NTOK * CC + c];
    __syncthreads();
    for (int o = tid; o < CC; o += 256) {
        float acc = qkv_b[o];
        for (int c = 0; c < CC; ++c)
            acc = fmaf(x0[c], qkv_w[(size_t)c * (3 * CC) + o], acc);
        q0ws[b * CC + o] = acc;
    }
}

__global__ __launch_bounds__(256)
void r_kernel(const float* __restrict__ qkv_w, const float* __restrict__ qkv_b,
              const float* __restrict__ q0ws, float* __restrict__ rws,
              float* __restrict__ bconst)
{
    const int blk = blockIdx.x;
    const int b = blk / HH, h = blk - b * HH;
    const int tid = threadIdx.x;
    __shared__ float q0h[DH];
    if (tid < DH) q0h[tid] = q0ws[b * CC + h * DH + tid];
    __syncthreads();
    for (int c = tid; c < CC; c += 256) {
        const float* wrow = qkv_w + (size_t)c * (3 * CC) + CC + h * DH;
        float acc = 0.f;
#pragma unroll
        for (int d = 0; d < DH; d += 4) {
            float4 w4 = *(const float4*)(wrow + d);
            acc = fmaf(w4.x, q0h[d + 0], acc);
            acc = fmaf(w4.y, q0h[d + 1], acc);
            acc = fmaf(w4.z, q0h[d + 2], acc);
            acc = fmaf(w4.w, q0h[d + 3], acc);
        }
        rws[((size_t)b * HH + h) * CC + c] = acc;
    }
    if (tid == 0) {
        float acc = 0.f;
        for (int d = 0; d < DH; ++d) acc += q0h[d] * qkv_b[CC + h * DH + d];
        bconst[blk] = acc;
    }
}

__global__ __launch_bounds__(256)
void cls_topk(const float* __restrict__ x, const float* __restrict__ rws,
              const float* __restrict__ bconst, float* __restrict__ out, int write_lt)
{
    const int b = blockIdx.x, tid = threadIdx.x;
    const int wave = tid >> 6, lane = tid & 63;
    __shared__ __align__(16) float rs[CC * HH];   // rs[c*12+h]
    __shared__ float sbuf[HH][208];
    __shared__ float pm[4][208];
    __shared__ float bc[HH];
    __shared__ float vals[256];
    __shared__ int   idxs[256];

    for (int f = tid; f < CC * HH; f += 256) {
        int h = f / CC, c = f - h * CC;
        rs[c * HH + h] = rws[((size_t)b * HH + h) * CC + c];
    }
    if (tid < HH) bc[tid] = bconst[b * HH + tid];
    for (int jj = lane; jj < 208; jj += 64) pm[wave][jj] = 0.f;
    __syncthreads();

    if (tid < NTOK) {
        float a12[HH];
#pragma unroll
        for (int h = 0; h < HH; ++h) a12[h] = 0.f;
        const float* xr = x + ((size_t)b * NTOK + tid) * CC;
        for (int c = 0; c < CC; ++c) {
            float xv = xr[c];
            float4 r0 = *(const float4*)&rs[c * 12];
            float4 r1 = *(const float4*)&rs[c * 12 + 4];
            float4 r2 = *(const float4*)&rs[c * 12 + 8];
            a12[0] = fmaf(xv, r0.x, a12[0]); a12[1] = fmaf(xv, r0.y, a12[1]);
            a12[2] = fmaf(xv, r0.z, a12[2]); a12[3] = fmaf(xv, r0.w, a12[3]);
            a12[4] = fmaf(xv, r1.x, a12[4]); a12[5] = fmaf(xv, r1.y, a12[5]);
            a12[6] = fmaf(xv, r1.z, a12[6]); a12[7] = fmaf(xv, r1.w, a12[7]);
            a12[8] = fmaf(xv, r2.x, a12[8]); a12[9] = fmaf(xv, r2.y, a12[9]);
            a12[10] = fmaf(xv, r2.z, a12[10]); a12[11] = fmaf(xv, r2.w, a12[11]);
        }
#pragma unroll
        for (int h = 0; h < HH; ++h) sbuf[h][tid] = (a12[h] + bc[h]) * 0.125f;
    }
    __syncthreads();

    for (int h = wave; h < HH; h += 4) {
        float sv[4], ev[4];
        float mx = -1e30f;
#pragma unroll
        for (int t = 0; t < 4; ++t) {
            int j = lane + 64 * t;
            sv[t] = (j < NTOK) ? sbuf[h][j] : -1e30f;
            mx = fmaxf(mx, sv[t]);
        }
#pragma unroll
        for (int off = 1; off < 64; off <<= 1) mx = fmaxf(mx, __shfl_xor(mx, off, 64));
        float sm = 0.f;
#pragma unroll
        for (int t = 0; t < 4; ++t) {
            int j = lane + 64 * t;
            ev[t] = (j < NTOK) ? expf(sv[t] - mx) : 0.f;
            sm += ev[t];
        }
#pragma unroll
        for (int off = 1; off < 64; off <<= 1) sm += __shfl_xor(sm, off, 64);
#pragma unroll
        for (int t = 0; t < 4; ++t) {
            int j = lane + 64 * t;
            if (j < NTOK) pm[wave][j] += ev[t] / sm;
        }
    }
    __syncthreads();

    float v = -INFINITY;
    int id = 256 + tid;
    if (tid < NTOK - 1) {
        int j = tid + 1;
        float s = ((pm[0][j] + pm[1][j]) + (pm[2][j] + pm[3][j])) * (1.f / 12.f);
        v = s; id = tid;
        out[CLS_OFF + (size_t)b * (NTOK - 1) + tid] = s;
    }
    vals[tid] = v; idxs[tid] = id;
    __syncthreads();

    for (int k = 2; k <= 256; k <<= 1) {
        for (int j = k >> 1; j > 0; j >>= 1) {
            int ixj = tid ^ j;
            if (ixj > tid) {
                float va = vals[tid], vb2 = vals[ixj];
                int ia = idxs[tid], ib = idxs[ixj];
                bool aLess = (va > vb2) || (va == vb2 && ia < ib);
                bool dir = ((tid & k) == 0);
                if (dir != aLess) {
                    vals[tid] = vb2; vals[ixj] = va;
                    idxs[tid] = ib;  idxs[ixj] = ia;
                }
            }
            __syncthreads();
        }
    }

    if (tid < LEFT) out[IDX_OFF + (size_t)b * LEFT + tid] = (float)idxs[tid];
    for (int u = tid; u < LEFT * CC; u += 256) {
        int t = u / CC;
        out[INDEX_OFF + (size_t)b * LEFT * CC + u] = (float)idxs[t];
    }
    if (write_lt && b == 0 && tid == 0) out[LT_OFF] = (float)LEFT;
}

// ---------------------------------------------------------------------------
extern "C" void kernel_launch(void* const* d_in, const int* in_sizes, int n_in,
                              void* d_out, int out_size, void* d_ws, size_t ws_size,
                              hipStream_t stream)
{
    const float* x      = (const float*)d_in[0];
    const float* qkv_w  = (const float*)d_in[1];
    const float* qkv_b  = (const float*)d_in[2];
    const float* proj_w = (const float*)d_in[3];
    const float* proj_b = (const float*)d_in[4];
    float* out = (float*)d_out;

    char* w = (char*)d_ws;
    unsigned short* xbf  = (unsigned short*)w; w += (size_t)MPAD * CC * 2;
    unsigned short* wt1  = (unsigned short*)w; w += (size_t)3 * CC * CC * 2;
    unsigned short* wt2  = (unsigned short*)w; w += (size_t)CC * CC * 2;
    unsigned short* qbf  = (unsigned short*)w; w += (size_t)BB * HH * NTOK * DH * 2;
    unsigned short* kbf  = (unsigned short*)w; w += (size_t)BB * HH * NTOK * DH * 2;
    unsigned short* vbf  = (unsigned short*)w; w += (size_t)BB * HH * NTOK * DH * 2;
    unsigned short* atbf = (unsigned short*)w; w += (size_t)MPAD * CC * 2;
    float* q0ws   = (float*)w; w += (size_t)BB * CC * 4;
    float* rws    = (float*)w; w += (size_t)BB * HH * CC * 4;
    float* bconst = (float*)w; w += (size_t)BB * HH * 4;

    convert_x<<<dim3(4728), 256, 0, stream>>>(x, xbf);
    transpose_w<<<dim3(24, 72), 256, 0, stream>>>(qkv_w, wt1, 3 * CC);
    transpose_w<<<dim3(24, 24), 256, 0, stream>>>(proj_w, wt2, CC);
    // 13 row bands of 8 row-tiles (99 -> guard), x ncolt col tiles, x 8 XCDs
    gemm_bf16<<<dim3(8 * 18 * 13), 256, 0, stream>>>(xbf, wt1, qkv_b, 18, 0,
                                                     qbf, kbf, vbf, nullptr);
    attn_mfma<<<dim3(BB * HH), 256, 0, stream>>>(qbf, kbf, vbf, atbf);
    gemm_bf16<<<dim3(8 * 6 * 13), 256, 0, stream>>>(atbf, wt2, proj_b, 6, 1,
                                                    nullptr, nullptr, nullptr, out + XOUT_OFF);
    q0_kernel<<<dim3(BB), 256, 0, stream>>>(x, qkv_w, qkv_b, q0ws);
    r_kernel<<<dim3(BB * HH), 256, 0, stream>>>(qkv_w, qkv_b, q0ws, rws, bconst);
    cls_topk<<<dim3(BB), 256, 0, stream>>>(x, rws, bconst, out, (out_size > LT_OFF) ? 1 : 0);
}

// Round 5
// 418.954 us; speedup vs baseline: 3.6497x; 1.0182x over previous
//
#include <hip/hip_runtime.h>
#include <math.h>

#define BB   64
#define NTOK 197
#define CC   768
#define HH   12
#define DH   64
#define MTOT (BB * NTOK)          // 12608
#define MPAD 12672                // 99*128
#define LEFT 138

// d_out layout (floats, concatenated in return order)
#define XOUT_OFF  0
#define INDEX_OFF 9682944         // B*N*C
#define IDX_OFF   16465920        // + B*138*C
#define CLS_OFF   16474752        // + B*138
#define LT_OFF    16487296        // + B*196

typedef short s8v __attribute__((ext_vector_type(8)));
typedef short s4v __attribute__((ext_vector_type(4)));
typedef float f4v __attribute__((ext_vector_type(4)));

#define GLOAD16(g, l) __builtin_amdgcn_global_load_lds( \
    (const __attribute__((address_space(1))) unsigned int*)(g), \
    (__attribute__((address_space(3))) unsigned int*)(l), 16, 0, 0)

__device__ __forceinline__ unsigned short f2bf(float f) {
    union { float f; unsigned int i; } x; x.f = f;
    unsigned int r = x.i + 0x7FFFu + ((x.i >> 16) & 1u);   // RNE
    return (unsigned short)(r >> 16);
}

// ---------------------------------------------------------------------------
// fp32 [M,768] -> bf16 [M,768]
// ---------------------------------------------------------------------------
__global__ __launch_bounds__(256)
void convert_x(const float* __restrict__ in, unsigned short* __restrict__ outb)
{
    size_t i = ((size_t)blockIdx.x * 256 + threadIdx.x) * 8;
    float4 a = *(const float4*)(in + i);
    float4 b = *(const float4*)(in + i + 4);
    s8v r;
    r[0] = (short)f2bf(a.x); r[1] = (short)f2bf(a.y);
    r[2] = (short)f2bf(a.z); r[3] = (short)f2bf(a.w);
    r[4] = (short)f2bf(b.x); r[5] = (short)f2bf(b.y);
    r[6] = (short)f2bf(b.z); r[7] = (short)f2bf(b.w);
    *(s8v*)(outb + i) = r;
}

// ---------------------------------------------------------------------------
// fp32 W [768,N] -> bf16 W^T [N,768]
// ---------------------------------------------------------------------------
__global__ __launch_bounds__(256)
void transpose_w(const float* __restrict__ in, unsigned short* __restrict__ outb, int N)
{
    __shared__ float tile[32][33];
    const int bi = blockIdx.x, bj = blockIdx.y;
    const int tx = threadIdx.x & 31, ty = threadIdx.x >> 5;
#pragma unroll
    for (int r = ty; r < 32; r += 8)
        tile[r][tx] = in[(size_t)(bi * 32 + r) * N + bj * 32 + tx];
    __syncthreads();
#pragma unroll
    for (int r = ty; r < 32; r += 8)
        outb[(size_t)(bj * 32 + r) * 768 + bi * 32 + tx] = f2bf(tile[tx][r]);
}

// ---------------------------------------------------------------------------
// bf16 MFMA GEMM: global_load_lds(16B) staging, XOR-swizzled LDS, 128x128
// tile, BK=64. MFMA operands SWAPPED (mfma(b,a)) so each lane's 4 acc regs
// are 4 consecutive OUTPUT COLUMNS at a fixed row -> vectorized stores.
// mode 0: bf16 out [M,2304] row-major (+bias); mode 1: fp32 out [M,768].
// ---------------------------------------------------------------------------
__global__ __launch_bounds__(256)
void gemm_bf16(const unsigned short* __restrict__ A, const unsigned short* __restrict__ BT,
               const float* __restrict__ bias, int ncolt, int mode,
               unsigned short* __restrict__ outb, float* __restrict__ outf)
{
    const int id = blockIdx.x;
    const int xcd = id & 7;
    const int t = id >> 3;
    const int ct = t % ncolt, s = t / ncolt;
    const int rt = s * 8 + xcd;
    if (rt >= 99) return;
    const int m0 = rt * 128, n0 = ct * 128;

    const int tid = threadIdx.x;
    const int wave = tid >> 6, lane = tid & 63;
    const int quad = lane >> 4, l16 = lane & 15;
    const int rowbase = (wave >> 1) * 64, colbase = (wave & 1) * 64;
    __shared__ __align__(16) short As[128 * 64];
    __shared__ __align__(16) short Bs[128 * 64];

    const int rA   = lane >> 3;
    const int gcol = ((lane & 7) ^ rA) * 8;
    const unsigned short* gA[4];
    const unsigned short* gB[4];
#pragma unroll
    for (int i = 0; i < 4; ++i) {
        int c = wave * 4 + i;
        gA[i] = A  + (size_t)(m0 + c * 8 + rA) * 768 + gcol;
        gB[i] = BT + (size_t)(n0 + c * 8 + rA) * 768 + gcol;
    }
    int aoff[4], boff[4];
#pragma unroll
    for (int i = 0; i < 4; ++i) {
        aoff[i] = (rowbase + i * 16 + l16) * 64 + ((quad ^ (l16 & 7)) * 8);
        boff[i] = (colbase + i * 16 + l16) * 64 + ((quad ^ (l16 & 7)) * 8);
    }

    f4v acc[4][4];
#pragma unroll
    for (int i = 0; i < 4; ++i)
#pragma unroll
        for (int j = 0; j < 4; ++j) acc[i][j] = (f4v)0.f;

    for (int k0 = 0; k0 < 768; k0 += 64) {
#pragma unroll
        for (int i = 0; i < 4; ++i) {
            int c = wave * 4 + i;
            GLOAD16(gA[i] + k0, &As[c * 512]);
            GLOAD16(gB[i] + k0, &Bs[c * 512]);
        }
        __syncthreads();
#pragma unroll
        for (int ks = 0; ks < 2; ++ks) {
            const int x = ks * 32;
            s8v af[4], bf[4];
#pragma unroll
            for (int i = 0; i < 4; ++i) af[i] = *(const s8v*)&As[aoff[i] ^ x];
#pragma unroll
            for (int j = 0; j < 4; ++j) bf[j] = *(const s8v*)&Bs[boff[j] ^ x];
#pragma unroll
            for (int i = 0; i < 4; ++i)
#pragma unroll
                for (int j = 0; j < 4; ++j)
                    acc[i][j] = __builtin_amdgcn_mfma_f32_16x16x32_bf16(bf[j], af[i], acc[i][j], 0, 0, 0);
        }
        __syncthreads();
    }

    const int ncols = mode ? 768 : 2304;
#pragma unroll
    for (int i = 0; i < 4; ++i) {
        const int m = m0 + rowbase + i * 16 + l16;
        if (m >= MTOT) continue;
#pragma unroll
        for (int j = 0; j < 4; ++j) {
            const int nb = n0 + colbase + j * 16 + quad * 4;
            float4 b4 = *(const float4*)&bias[nb];
            if (mode == 1) {
                float4 r;
                r.x = acc[i][j][0] + b4.x; r.y = acc[i][j][1] + b4.y;
                r.z = acc[i][j][2] + b4.z; r.w = acc[i][j][3] + b4.w;
                *(float4*)(outf + (size_t)m * ncols + nb) = r;
            } else {
                s4v r;
                r[0] = (short)f2bf(acc[i][j][0] + b4.x);
                r[1] = (short)f2bf(acc[i][j][1] + b4.y);
                r[2] = (short)f2bf(acc[i][j][2] + b4.z);
                r[3] = (short)f2bf(acc[i][j][3] + b4.w);
                *(s4v*)(outb + (size_t)m * ncols + nb) = r;
            }
        }
    }
}

// ---------------------------------------------------------------------------
// MFMA attention per (b,h), reading row-major qkv [M,2304]. Operand-swapped
// QK^T (lane holds 4 consecutive keys per query=l16) and PV (lane holds 4
// consecutive d-dims per query) -> b64 LDS/global traffic, 2-shuffle softmax,
// row-sum lands at the lane PV needs it at.
// ---------------------------------------------------------------------------
#define PSTR 228   // shorts; 114 words/row, gcd(114,32)=2 -> 2-way alias only

__global__ __launch_bounds__(256)
void attn_mfma(const unsigned short* __restrict__ qkv, unsigned short* __restrict__ attnbf)
{
    const int bh = blockIdx.x;
    const int b = bh / HH, h = bh - b * HH;
    const int tid = threadIdx.x;
    const int wave = tid >> 6, lane = tid & 63;
    const int quad = lane >> 4, l16 = lane & 15;
    __shared__ short Vs[64 * PSTR];        // V^T [dd][tok]
    __shared__ short Ps[4][16 * PSTR];     // per-wave P [query][key]

    const unsigned short* qg = qkv + (size_t)b * NTOK * 2304 + h * DH;
    const unsigned short* kg = qg + 768;
    const unsigned short* vg = qg + 1536;

    if (tid < NTOK) {
#pragma unroll
        for (int c = 0; c < 8; ++c) {
            s8v vv = *(const s8v*)(vg + (size_t)tid * 2304 + c * 8);
#pragma unroll
            for (int e = 0; e < 8; ++e) Vs[(c * 8 + e) * PSTR + tid] = vv[e];
        }
    }
    for (int f = tid; f < 64 * (PSTR - NTOK); f += 256) {
        int dd = f / (PSTR - NTOK);
        int tk = NTOK + (f - dd * (PSTR - NTOK));
        Vs[dd * PSTR + tk] = 0;
    }
    __syncthreads();

    for (int strip = wave; strip < 13; strip += 4) {
        const int mq = min(strip * 16 + l16, NTOK - 1);
        const s8v aq0 = *(const s8v*)(qg + (size_t)mq * 2304 + quad * 8);
        const s8v aq1 = *(const s8v*)(qg + (size_t)mq * 2304 + 32 + quad * 8);

        f4v sacc[14];
#pragma unroll
        for (int j = 0; j < 14; ++j) sacc[j] = (f4v)0.f;
#pragma unroll
        for (int j = 0; j < 14; ++j) {
            const int kt = min(j * 16 + l16, NTOK - 1);
            s8v bk0 = *(const s8v*)(kg + (size_t)kt * 2304 + quad * 8);
            s8v bk1 = *(const s8v*)(kg + (size_t)kt * 2304 + 32 + quad * 8);
            sacc[j] = __builtin_amdgcn_mfma_f32_16x16x32_bf16(bk0, aq0, sacc[j], 0, 0, 0);
            sacc[j] = __builtin_amdgcn_mfma_f32_16x16x32_bf16(bk1, aq1, sacc[j], 0, 0, 0);
        }

        // D[key-offset][query]: row=quad*4+reg -> key=j*16+quad*4+reg, col=l16 -> query
        float mx = -1e30f;
#pragma unroll
        for (int j = 0; j < 14; ++j)
#pragma unroll
            for (int r = 0; r < 4; ++r) {
                const int key = j * 16 + quad * 4 + r;
                float s = (key < NTOK) ? sacc[j][r] * 0.125f : -1e30f;
                sacc[j][r] = s;
                mx = fmaxf(mx, s);
            }
        mx = fmaxf(mx, __shfl_xor(mx, 16, 64));
        mx = fmaxf(mx, __shfl_xor(mx, 32, 64));

        float sm = 0.f;
#pragma unroll
        for (int j = 0; j < 14; ++j) {
            s4v pk;
#pragma unroll
            for (int r = 0; r < 4; ++r) {
                const int key = j * 16 + quad * 4 + r;
                float p = (key < NTOK) ? __expf(sacc[j][r] - mx) : 0.f;
                sm += p;
                pk[r] = (short)f2bf(p);
            }
            *(s4v*)&Ps[wave][l16 * PSTR + j * 16 + quad * 4] = pk;
        }
        sm += __shfl_xor(sm, 16, 64);
        sm += __shfl_xor(sm, 32, 64);
        const float rcp = 1.f / sm;

        f4v oacc[4];
#pragma unroll
        for (int j = 0; j < 4; ++j) oacc[j] = (f4v)0.f;
#pragma unroll
        for (int t = 0; t < 7; ++t) {
            const int ko = t * 32 + quad * 8;
            s8v ap = *(const s8v*)&Ps[wave][l16 * PSTR + ko];
#pragma unroll
            for (int j = 0; j < 4; ++j) {
                s8v bv = *(const s8v*)&Vs[(j * 16 + l16) * PSTR + ko];
                oacc[j] = __builtin_amdgcn_mfma_f32_16x16x32_bf16(bv, ap, oacc[j], 0, 0, 0);
            }
        }
        const int qrow = strip * 16 + l16;
        if (qrow < NTOK) {
#pragma unroll
            for (int j = 0; j < 4; ++j) {
                s4v o4;
#pragma unroll
                for (int r = 0; r < 4; ++r) o4[r] = (short)f2bf(oacc[j][r] * rcp);
                *(s4v*)&attnbf[((size_t)b * NTOK + qrow) * 768 + h * DH + j * 16 + quad * 4] = o4;
            }
        }
    }
}

// ---------------------------------------------------------------------------
// Exact fp32 cls path — REVERTED to round-3 serial form (passed rounds 2-3).
// The cls accumulation association is load-bearing for top-k rank stability:
// the round-4 2-way K split flipped a near-tie. Do not re-split.
// ---------------------------------------------------------------------------
__global__ __launch_bounds__(256)
void q0_kernel(const float* __restrict__ x, const float* __restrict__ qkv_w,
               const float* __restrict__ qkv_b, float* __restrict__ q0ws)
{
    const int b = blockIdx.x, tid = threadIdx.x;
    __shared__ float x0[CC];
    for (int c = tid; c < CC; c += 256) x0[c] = x[(size_t)b * NTOK * CC + c];
    __syncthreads();
    for (int o = tid; o < CC; o += 256) {
        float acc = qkv_b[o];
        for (int c = 0; c < CC; ++c)
            acc = fmaf(x0[c], qkv_w[(size_t)c * (3 * CC) + o], acc);
        q0ws[b * CC + o] = acc;
    }
}

__global__ __launch_bounds__(256)
void r_kernel(const float* __restrict__ qkv_w, const float* __restrict__ qkv_b,
              const float* __restrict__ q0ws, float* __restrict__ rws,
              float* __restrict__ bconst)
{
    const int blk = blockIdx.x;
    const int b = blk / HH, h = blk - b * HH;
    const int tid = threadIdx.x;
    __shared__ float q0h[DH];
    if (tid < DH) q0h[tid] = q0ws[b * CC + h * DH + tid];
    __syncthreads();
    for (int c = tid; c < CC; c += 256) {
        const float* wrow = qkv_w + (size_t)c * (3 * CC) + CC + h * DH;
        float acc = 0.f;
#pragma unroll
        for (int d = 0; d < DH; d += 4) {
            float4 w4 = *(const float4*)(wrow + d);
            acc = fmaf(w4.x, q0h[d + 0], acc);
            acc = fmaf(w4.y, q0h[d + 1], acc);
            acc = fmaf(w4.z, q0h[d + 2], acc);
            acc = fmaf(w4.w, q0h[d + 3], acc);
        }
        rws[((size_t)b * HH + h) * CC + c] = acc;
    }
    if (tid == 0) {
        float acc = 0.f;
        for (int d = 0; d < DH; ++d) acc += q0h[d] * qkv_b[CC + h * DH + d];
        bconst[blk] = acc;
    }
}

__global__ __launch_bounds__(256)
void cls_topk(const float* __restrict__ x, const float* __restrict__ rws,
              const float* __restrict__ bconst, float* __restrict__ out, int write_lt)
{
    const int b = blockIdx.x, tid = threadIdx.x;
    const int wave = tid >> 6, lane = tid & 63;
    __shared__ __align__(16) float rs[CC * HH];
    __shared__ float sbuf[HH][208];
    __shared__ float pm[4][208];
    __shared__ float bc[HH];
    __shared__ float vals[256];
    __shared__ int   idxs[256];

    for (int f = tid; f < CC * HH; f += 256) {
        int h = f / CC, c = f - h * CC;
        rs[c * HH + h] = rws[((size_t)b * HH + h) * CC + c];
    }
    if (tid < HH) bc[tid] = bconst[b * HH + tid];
    for (int jj = lane; jj < 208; jj += 64) pm[wave][jj] = 0.f;
    __syncthreads();

    if (tid < NTOK) {
        float a12[HH];
#pragma unroll
        for (int h = 0; h < HH; ++h) a12[h] = 0.f;
        const float* xr = x + ((size_t)b * NTOK + tid) * CC;
        for (int c = 0; c < CC; ++c) {
            float xv = xr[c];
            float4 r0 = *(const float4*)&rs[c * 12];
            float4 r1 = *(const float4*)&rs[c * 12 + 4];
            float4 r2 = *(const float4*)&rs[c * 12 + 8];
            a12[0] = fmaf(xv, r0.x, a12[0]); a12[1] = fmaf(xv, r0.y, a12[1]);
            a12[2] = fmaf(xv, r0.z, a12[2]); a12[3] = fmaf(xv, r0.w, a12[3]);
            a12[4] = fmaf(xv, r1.x, a12[4]); a12[5] = fmaf(xv, r1.y, a12[5]);
            a12[6] = fmaf(xv, r1.z, a12[6]); a12[7] = fmaf(xv, r1.w, a12[7]);
            a12[8] = fmaf(xv, r2.x, a12[8]); a12[9] = fmaf(xv, r2.y, a12[9]);
            a12[10] = fmaf(xv, r2.z, a12[10]); a12[11] = fmaf(xv, r2.w, a12[11]);
        }
#pragma unroll
        for (int h = 0; h < HH; ++h) sbuf[h][tid] = (a12[h] + bc[h]) * 0.125f;
    }
    __syncthreads();

    for (int h = wave; h < HH; h += 4) {
        float sv[4], ev[4];
        float mx = -1e30f;
#pragma unroll
        for (int t = 0; t < 4; ++t) {
            int j = lane + 64 * t;
            sv[t] = (j < NTOK) ? sbuf[h][j] : -1e30f;
            mx = fmaxf(mx, sv[t]);
        }
#pragma unroll
        for (int off = 1; off < 64; off <<= 1) mx = fmaxf(mx, __shfl_xor(mx, off, 64));
        float sm = 0.f;
#pragma unroll
        for (int t = 0; t < 4; ++t) {
            int j = lane + 64 * t;
            ev[t] = (j < NTOK) ? expf(sv[t] - mx) : 0.f;
            sm += ev[t];
        }
#pragma unroll
        for (int off = 1; off < 64; off <<= 1) sm += __shfl_xor(sm, off, 64);
#pragma unroll
        for (int t = 0; t < 4; ++t) {
            int j = lane + 64 * t;
            if (j < NTOK) pm[wave][j] += ev[t] / sm;
        }
    }
    __syncthreads();

    float v = -INFINITY;
    int id = 256 + tid;
    if (tid < NTOK - 1) {
        int j = tid + 1;
        float s = ((pm[0][j] + pm[1][j]) + (pm[2][j] + pm[3][j])) * (1.f / 12.f);
        v = s; id = tid;
        out[CLS_OFF + (size_t)b * (NTOK - 1) + tid] = s;
    }
    vals[tid] = v; idxs[tid] = id;
    __syncthreads();

    for (int k = 2; k <= 256; k <<= 1) {
        for (int j = k >> 1; j > 0; j >>= 1) {
            int ixj = tid ^ j;
            if (ixj > tid) {
                float va = vals[tid], vb2 = vals[ixj];
                int ia = idxs[tid], ib = idxs[ixj];
                bool aLess = (va > vb2) || (va == vb2 && ia < ib);
                bool dir = ((tid & k) == 0);
                if (dir != aLess) {
                    vals[tid] = vb2; vals[ixj] = va;
                    idxs[tid] = ib;  idxs[ixj] = ia;
                }
            }
            __syncthreads();
        }
    }

    if (tid < LEFT) out[IDX_OFF + (size_t)b * LEFT + tid] = (float)idxs[tid];
    for (int u = tid; u < LEFT * CC; u += 256) {
        int t = u / CC;
        out[INDEX_OFF + (size_t)b * LEFT * CC + u] = (float)idxs[t];
    }
    if (write_lt && b == 0 && tid == 0) out[LT_OFF] = (float)LEFT;
}

// ---------------------------------------------------------------------------
extern "C" void kernel_launch(void* const* d_in, const int* in_sizes, int n_in,
                              void* d_out, int out_size, void* d_ws, size_t ws_size,
                              hipStream_t stream)
{
    const float* x      = (const float*)d_in[0];
    const float* qkv_w  = (const float*)d_in[1];
    const float* qkv_b  = (const float*)d_in[2];
    const float* proj_w = (const float*)d_in[3];
    const float* proj_b = (const float*)d_in[4];
    float* out = (float*)d_out;

    char* w = (char*)d_ws;
    unsigned short* xbf   = (unsigned short*)w; w += (size_t)MPAD * CC * 2;
    unsigned short* wt1   = (unsigned short*)w; w += (size_t)3 * CC * CC * 2;
    unsigned short* wt2   = (unsigned short*)w; w += (size_t)CC * CC * 2;
    unsigned short* qkvbf = (unsigned short*)w; w += (size_t)MTOT * 3 * CC * 2;
    unsigned short* atbf  = (unsigned short*)w; w += (size_t)MPAD * CC * 2;
    float* q0ws   = (float*)w; w += (size_t)BB * CC * 4;
    float* rws    = (float*)w; w += (size_t)BB * HH * CC * 4;
    float* bconst = (float*)w; w += (size_t)BB * HH * 4;

    convert_x<<<dim3(4728), 256, 0, stream>>>(x, xbf);
    transpose_w<<<dim3(24, 72), 256, 0, stream>>>(qkv_w, wt1, 3 * CC);
    transpose_w<<<dim3(24, 24), 256, 0, stream>>>(proj_w, wt2, CC);
    gemm_bf16<<<dim3(8 * 18 * 13), 256, 0, stream>>>(xbf, wt1, qkv_b, 18, 0, qkvbf, nullptr);
    attn_mfma<<<dim3(BB * HH), 256, 0, stream>>>(qkvbf, atbf);
    gemm_bf16<<<dim3(8 * 6 * 13), 256, 0, stream>>>(atbf, wt2, proj_b, 6, 1,
                                                    nullptr, out + XOUT_OFF);
    q0_kernel<<<dim3(BB), 256, 0, stream>>>(x, qkv_w, qkv_b, q0ws);
    r_kernel<<<dim3(BB * HH), 256, 0, stream>>>(qkv_w, qkv_b, q0ws, rws, bconst);
    cls_topk<<<dim3(BB), 256, 0, stream>>>(x, rws, bconst, out, (out_size > LT_OFF) ? 1 : 0);
}

// Round 6
// 388.097 us; speedup vs baseline: 3.9399x; 1.0795x over previous
//
#include <hip/hip_runtime.h>
#include <math.h>

#define BB   64
#define NTOK 197
#define CC   768
#define HH   12
#define DH   64
#define MTOT (BB * NTOK)          // 12608
#define MPAD 12672                // 99*128
#define LEFT 138

// d_out layout (floats, concatenated in return order)
#define XOUT_OFF  0
#define INDEX_OFF 9682944         // B*N*C
#define IDX_OFF   16465920        // + B*138*C
#define CLS_OFF   16474752        // + B*138
#define LT_OFF    16487296        // + B*196

typedef short s8v __attribute__((ext_vector_type(8)));
typedef short s4v __attribute__((ext_vector_type(4)));
typedef float f4v __attribute__((ext_vector_type(4)));

#define GLOAD16(g, l) __builtin_amdgcn_global_load_lds( \
    (const __attribute__((address_space(1))) unsigned int*)(g), \
    (__attribute__((address_space(3))) unsigned int*)(l), 16, 0, 0)

__device__ __forceinline__ unsigned short f2bf(float f) {
    union { float f; unsigned int i; } x; x.f = f;
    unsigned int r = x.i + 0x7FFFu + ((x.i >> 16) & 1u);   // RNE
    return (unsigned short)(r >> 16);
}

// ---------------------------------------------------------------------------
// fp32 [M,768] -> bf16 [M,768]
// ---------------------------------------------------------------------------
__global__ __launch_bounds__(256)
void convert_x(const float* __restrict__ in, unsigned short* __restrict__ outb)
{
    size_t i = ((size_t)blockIdx.x * 256 + threadIdx.x) * 8;
    float4 a = *(const float4*)(in + i);
    float4 b = *(const float4*)(in + i + 4);
    s8v r;
    r[0] = (short)f2bf(a.x); r[1] = (short)f2bf(a.y);
    r[2] = (short)f2bf(a.z); r[3] = (short)f2bf(a.w);
    r[4] = (short)f2bf(b.x); r[5] = (short)f2bf(b.y);
    r[6] = (short)f2bf(b.z); r[7] = (short)f2bf(b.w);
    *(s8v*)(outb + i) = r;
}

// ---------------------------------------------------------------------------
// fp32 W [768,N] -> bf16 W^T [N,768]
// ---------------------------------------------------------------------------
__global__ __launch_bounds__(256)
void transpose_w(const float* __restrict__ in, unsigned short* __restrict__ outb, int N)
{
    __shared__ float tile[32][33];
    const int bi = blockIdx.x, bj = blockIdx.y;
    const int tx = threadIdx.x & 31, ty = threadIdx.x >> 5;
#pragma unroll
    for (int r = ty; r < 32; r += 8)
        tile[r][tx] = in[(size_t)(bi * 32 + r) * N + bj * 32 + tx];
    __syncthreads();
#pragma unroll
    for (int r = ty; r < 32; r += 8)
        outb[(size_t)(bj * 32 + r) * 768 + bi * 32 + tx] = f2bf(tile[tx][r]);
}

// ---------------------------------------------------------------------------
// bf16 MFMA GEMM (unchanged from round 5): global_load_lds staging, XOR
// swizzle, swapped operands for column-vectorized epilogue.
// ---------------------------------------------------------------------------
__global__ __launch_bounds__(256)
void gemm_bf16(const unsigned short* __restrict__ A, const unsigned short* __restrict__ BT,
               const float* __restrict__ bias, int ncolt, int mode,
               unsigned short* __restrict__ outb, float* __restrict__ outf)
{
    const int id = blockIdx.x;
    const int xcd = id & 7;
    const int t = id >> 3;
    const int ct = t % ncolt, s = t / ncolt;
    const int rt = s * 8 + xcd;
    if (rt >= 99) return;
    const int m0 = rt * 128, n0 = ct * 128;

    const int tid = threadIdx.x;
    const int wave = tid >> 6, lane = tid & 63;
    const int quad = lane >> 4, l16 = lane & 15;
    const int rowbase = (wave >> 1) * 64, colbase = (wave & 1) * 64;
    __shared__ __align__(16) short As[128 * 64];
    __shared__ __align__(16) short Bs[128 * 64];

    const int rA   = lane >> 3;
    const int gcol = ((lane & 7) ^ rA) * 8;
    const unsigned short* gA[4];
    const unsigned short* gB[4];
#pragma unroll
    for (int i = 0; i < 4; ++i) {
        int c = wave * 4 + i;
        gA[i] = A  + (size_t)(m0 + c * 8 + rA) * 768 + gcol;
        gB[i] = BT + (size_t)(n0 + c * 8 + rA) * 768 + gcol;
    }
    int aoff[4], boff[4];
#pragma unroll
    for (int i = 0; i < 4; ++i) {
        aoff[i] = (rowbase + i * 16 + l16) * 64 + ((quad ^ (l16 & 7)) * 8);
        boff[i] = (colbase + i * 16 + l16) * 64 + ((quad ^ (l16 & 7)) * 8);
    }

    f4v acc[4][4];
#pragma unroll
    for (int i = 0; i < 4; ++i)
#pragma unroll
        for (int j = 0; j < 4; ++j) acc[i][j] = (f4v)0.f;

    for (int k0 = 0; k0 < 768; k0 += 64) {
#pragma unroll
        for (int i = 0; i < 4; ++i) {
            int c = wave * 4 + i;
            GLOAD16(gA[i] + k0, &As[c * 512]);
            GLOAD16(gB[i] + k0, &Bs[c * 512]);
        }
        __syncthreads();
#pragma unroll
        for (int ks = 0; ks < 2; ++ks) {
            const int x = ks * 32;
            s8v af[4], bf[4];
#pragma unroll
            for (int i = 0; i < 4; ++i) af[i] = *(const s8v*)&As[aoff[i] ^ x];
#pragma unroll
            for (int j = 0; j < 4; ++j) bf[j] = *(const s8v*)&Bs[boff[j] ^ x];
#pragma unroll
            for (int i = 0; i < 4; ++i)
#pragma unroll
                for (int j = 0; j < 4; ++j)
                    acc[i][j] = __builtin_amdgcn_mfma_f32_16x16x32_bf16(bf[j], af[i], acc[i][j], 0, 0, 0);
        }
        __syncthreads();
    }

    const int ncols = mode ? 768 : 2304;
#pragma unroll
    for (int i = 0; i < 4; ++i) {
        const int m = m0 + rowbase + i * 16 + l16;
        if (m >= MTOT) continue;
#pragma unroll
        for (int j = 0; j < 4; ++j) {
            const int nb = n0 + colbase + j * 16 + quad * 4;
            float4 b4 = *(const float4*)&bias[nb];
            if (mode == 1) {
                float4 r;
                r.x = acc[i][j][0] + b4.x; r.y = acc[i][j][1] + b4.y;
                r.z = acc[i][j][2] + b4.z; r.w = acc[i][j][3] + b4.w;
                *(float4*)(outf + (size_t)m * ncols + nb) = r;
            } else {
                s4v r;
                r[0] = (short)f2bf(acc[i][j][0] + b4.x);
                r[1] = (short)f2bf(acc[i][j][1] + b4.y);
                r[2] = (short)f2bf(acc[i][j][2] + b4.z);
                r[3] = (short)f2bf(acc[i][j][3] + b4.w);
                *(s4v*)(outb + (size_t)m * ncols + nb) = r;
            }
        }
    }
}

// ---------------------------------------------------------------------------
// MFMA attention per (b,h) (unchanged from round 5).
// ---------------------------------------------------------------------------
#define PSTR 228

__global__ __launch_bounds__(256)
void attn_mfma(const unsigned short* __restrict__ qkv, unsigned short* __restrict__ attnbf)
{
    const int bh = blockIdx.x;
    const int b = bh / HH, h = bh - b * HH;
    const int tid = threadIdx.x;
    const int wave = tid >> 6, lane = tid & 63;
    const int quad = lane >> 4, l16 = lane & 15;
    __shared__ short Vs[64 * PSTR];        // V^T [dd][tok]
    __shared__ short Ps[4][16 * PSTR];     // per-wave P [query][key]

    const unsigned short* qg = qkv + (size_t)b * NTOK * 2304 + h * DH;
    const unsigned short* kg = qg + 768;
    const unsigned short* vg = qg + 1536;

    if (tid < NTOK) {
#pragma unroll
        for (int c = 0; c < 8; ++c) {
            s8v vv = *(const s8v*)(vg + (size_t)tid * 2304 + c * 8);
#pragma unroll
            for (int e = 0; e < 8; ++e) Vs[(c * 8 + e) * PSTR + tid] = vv[e];
        }
    }
    for (int f = tid; f < 64 * (PSTR - NTOK); f += 256) {
        int dd = f / (PSTR - NTOK);
        int tk = NTOK + (f - dd * (PSTR - NTOK));
        Vs[dd * PSTR + tk] = 0;
    }
    __syncthreads();

    for (int strip = wave; strip < 13; strip += 4) {
        const int mq = min(strip * 16 + l16, NTOK - 1);
        const s8v aq0 = *(const s8v*)(qg + (size_t)mq * 2304 + quad * 8);
        const s8v aq1 = *(const s8v*)(qg + (size_t)mq * 2304 + 32 + quad * 8);

        f4v sacc[14];
#pragma unroll
        for (int j = 0; j < 14; ++j) sacc[j] = (f4v)0.f;
#pragma unroll
        for (int j = 0; j < 14; ++j) {
            const int kt = min(j * 16 + l16, NTOK - 1);
            s8v bk0 = *(const s8v*)(kg + (size_t)kt * 2304 + quad * 8);
            s8v bk1 = *(const s8v*)(kg + (size_t)kt * 2304 + 32 + quad * 8);
            sacc[j] = __builtin_amdgcn_mfma_f32_16x16x32_bf16(bk0, aq0, sacc[j], 0, 0, 0);
            sacc[j] = __builtin_amdgcn_mfma_f32_16x16x32_bf16(bk1, aq1, sacc[j], 0, 0, 0);
        }

        float mx = -1e30f;
#pragma unroll
        for (int j = 0; j < 14; ++j)
#pragma unroll
            for (int r = 0; r < 4; ++r) {
                const int key = j * 16 + quad * 4 + r;
                float s = (key < NTOK) ? sacc[j][r] * 0.125f : -1e30f;
                sacc[j][r] = s;
                mx = fmaxf(mx, s);
            }
        mx = fmaxf(mx, __shfl_xor(mx, 16, 64));
        mx = fmaxf(mx, __shfl_xor(mx, 32, 64));

        float sm = 0.f;
#pragma unroll
        for (int j = 0; j < 14; ++j) {
            s4v pk;
#pragma unroll
            for (int r = 0; r < 4; ++r) {
                const int key = j * 16 + quad * 4 + r;
                float p = (key < NTOK) ? __expf(sacc[j][r] - mx) : 0.f;
                sm += p;
                pk[r] = (short)f2bf(p);
            }
            *(s4v*)&Ps[wave][l16 * PSTR + j * 16 + quad * 4] = pk;
        }
        sm += __shfl_xor(sm, 16, 64);
        sm += __shfl_xor(sm, 32, 64);
        const float rcp = 1.f / sm;

        f4v oacc[4];
#pragma unroll
        for (int j = 0; j < 4; ++j) oacc[j] = (f4v)0.f;
#pragma unroll
        for (int t = 0; t < 7; ++t) {
            const int ko = t * 32 + quad * 8;
            s8v ap = *(const s8v*)&Ps[wave][l16 * PSTR + ko];
#pragma unroll
            for (int j = 0; j < 4; ++j) {
                s8v bv = *(const s8v*)&Vs[(j * 16 + l16) * PSTR + ko];
                oacc[j] = __builtin_amdgcn_mfma_f32_16x16x32_bf16(bv, ap, oacc[j], 0, 0, 0);
            }
        }
        const int qrow = strip * 16 + l16;
        if (qrow < NTOK) {
#pragma unroll
            for (int j = 0; j < 4; ++j) {
                s4v o4;
#pragma unroll
                for (int r = 0; r < 4; ++r) o4[r] = (short)f2bf(oacc[j][r] * rcp);
                *(s4v*)&attnbf[((size_t)b * NTOK + qrow) * 768 + h * DH + j * 16 + quad * 4] = o4;
            }
        }
    }
}

// ---------------------------------------------------------------------------
// Exact fp32 cls path. ASSOCIATION ORDER IS LOAD-BEARING (round-4 failure):
// every serial chain below is bitwise-identical to the round-5 passing code;
// only the block/thread placement changed (parallel over (b,h), not split-K).
// ---------------------------------------------------------------------------
// qr_kernel: per (b,h): q0h[d] (bias-first, c-ascending chain), bconst,
// rws[b,h,c] (d-ascending float4 chain). 768 blocks.
__global__ __launch_bounds__(256)
void qr_kernel(const float* __restrict__ x, const float* __restrict__ qkv_w,
               const float* __restrict__ qkv_b, float* __restrict__ rws,
               float* __restrict__ bconst)
{
    const int blk = blockIdx.x;
    const int b = blk / HH, h = blk - b * HH;
    const int tid = threadIdx.x;
    __shared__ float x0[CC];
    __shared__ float q0h[DH];
    for (int c = tid; c < CC; c += 256) x0[c] = x[(size_t)b * NTOK * CC + c];
    __syncthreads();
    if (tid < DH) {
        const int o = h * DH + tid;
        float acc = qkv_b[o];                       // identical to old q0_kernel
        for (int c = 0; c < CC; ++c)
            acc = fmaf(x0[c], qkv_w[(size_t)c * 2304 + o], acc);
        q0h[tid] = acc;
    }
    __syncthreads();
    for (int c = tid; c < CC; c += 256) {           // identical to old r_kernel
        const float* wrow = qkv_w + (size_t)c * 2304 + CC + h * DH;
        float acc = 0.f;
#pragma unroll
        for (int d = 0; d < DH; d += 4) {
            float4 w4 = *(const float4*)(wrow + d);
            acc = fmaf(w4.x, q0h[d + 0], acc);
            acc = fmaf(w4.y, q0h[d + 1], acc);
            acc = fmaf(w4.z, q0h[d + 2], acc);
            acc = fmaf(w4.w, q0h[d + 3], acc);
        }
        rws[((size_t)b * HH + h) * CC + c] = acc;
    }
    if (tid == 0) {
        float acc = 0.f;
        for (int d = 0; d < DH; ++d) acc += q0h[d] * qkv_b[CC + h * DH + d];
        bconst[blk] = acc;
    }
}

// cls_s: s[b,h,tok] = (x[b,tok,:].r[b,h,:] + bc)*0.125, single c-ascending
// chain per (tok,h) — identical op sequence to the round-5 in-topk loop.
// 1D grid 768, id = h*64+b so all h-blocks of a batch share an XCD.
__global__ __launch_bounds__(256)
void cls_s(const float* __restrict__ x, const float* __restrict__ rws,
           const float* __restrict__ bconst, float* __restrict__ sws)
{
    const int id = blockIdx.x;
    const int b = id & 63, h = id >> 6;
    const int tid = threadIdx.x;
    __shared__ __align__(16) float rl[CC];
    __shared__ float bcs;
    for (int c = tid; c < CC; c += 256) rl[c] = rws[((size_t)b * HH + h) * CC + c];
    if (tid == 0) bcs = bconst[b * HH + h];
    __syncthreads();
    if (tid < NTOK) {
        const float* xr = x + ((size_t)b * NTOK + tid) * CC;
        float acc = 0.f;
        for (int c = 0; c < CC; c += 4) {
            float4 r4 = *(const float4*)&rl[c];
            float4 x4 = *(const float4*)(xr + c);
            acc = fmaf(x4.x, r4.x, acc);
            acc = fmaf(x4.y, r4.y, acc);
            acc = fmaf(x4.z, r4.z, acc);
            acc = fmaf(x4.w, r4.w, acc);
        }
        sws[((size_t)b * HH + h) * NTOK + tid] = (acc + bcs) * 0.125f;
    }
}

// cls_topk: read s, then EXACT round-5 softmax/mean/bitonic/write code.
__global__ __launch_bounds__(256)
void cls_topk(const float* __restrict__ sws, float* __restrict__ out, int write_lt)
{
    const int b = blockIdx.x, tid = threadIdx.x;
    const int wave = tid >> 6, lane = tid & 63;
    __shared__ float sbuf[HH][208];
    __shared__ float pm[4][208];
    __shared__ float vals[256];
    __shared__ int   idxs[256];

    for (int jj = lane; jj < 208; jj += 64) pm[wave][jj] = 0.f;
    if (tid < NTOK) {
#pragma unroll
        for (int h = 0; h < HH; ++h)
            sbuf[h][tid] = sws[((size_t)b * HH + h) * NTOK + tid];
    }
    __syncthreads();

    for (int h = wave; h < HH; h += 4) {
        float sv[4], ev[4];
        float mx = -1e30f;
#pragma unroll
        for (int t = 0; t < 4; ++t) {
            int j = lane + 64 * t;
            sv[t] = (j < NTOK) ? sbuf[h][j] : -1e30f;
            mx = fmaxf(mx, sv[t]);
        }
#pragma unroll
        for (int off = 1; off < 64; off <<= 1) mx = fmaxf(mx, __shfl_xor(mx, off, 64));
        float sm = 0.f;
#pragma unroll
        for (int t = 0; t < 4; ++t) {
            int j = lane + 64 * t;
            ev[t] = (j < NTOK) ? expf(sv[t] - mx) : 0.f;
            sm += ev[t];
        }
#pragma unroll
        for (int off = 1; off < 64; off <<= 1) sm += __shfl_xor(sm, off, 64);
#pragma unroll
        for (int t = 0; t < 4; ++t) {
            int j = lane + 64 * t;
            if (j < NTOK) pm[wave][j] += ev[t] / sm;
        }
    }
    __syncthreads();

    float v = -INFINITY;
    int id = 256 + tid;
    if (tid < NTOK - 1) {
        int j = tid + 1;
        float s = ((pm[0][j] + pm[1][j]) + (pm[2][j] + pm[3][j])) * (1.f / 12.f);
        v = s; id = tid;
        out[CLS_OFF + (size_t)b * (NTOK - 1) + tid] = s;
    }
    vals[tid] = v; idxs[tid] = id;
    __syncthreads();

    for (int k = 2; k <= 256; k <<= 1) {
        for (int j = k >> 1; j > 0; j >>= 1) {
            int ixj = tid ^ j;
            if (ixj > tid) {
                float va = vals[tid], vb2 = vals[ixj];
                int ia = idxs[tid], ib = idxs[ixj];
                bool aLess = (va > vb2) || (va == vb2 && ia < ib);
                bool dir = ((tid & k) == 0);
                if (dir != aLess) {
                    vals[tid] = vb2; vals[ixj] = va;
                    idxs[tid] = ib;  idxs[ixj] = ia;
                }
            }
            __syncthreads();
        }
    }

    if (tid < LEFT) out[IDX_OFF + (size_t)b * LEFT + tid] = (float)idxs[tid];
    for (int u = tid; u < LEFT * CC; u += 256) {
        int t = u / CC;
        out[INDEX_OFF + (size_t)b * LEFT * CC + u] = (float)idxs[t];
    }
    if (write_lt && b == 0 && tid == 0) out[LT_OFF] = (float)LEFT;
}

// ---------------------------------------------------------------------------
extern "C" void kernel_launch(void* const* d_in, const int* in_sizes, int n_in,
                              void* d_out, int out_size, void* d_ws, size_t ws_size,
                              hipStream_t stream)
{
    const float* x      = (const float*)d_in[0];
    const float* qkv_w  = (const float*)d_in[1];
    const float* qkv_b  = (const float*)d_in[2];
    const float* proj_w = (const float*)d_in[3];
    const float* proj_b = (const float*)d_in[4];
    float* out = (float*)d_out;

    char* w = (char*)d_ws;
    unsigned short* xbf   = (unsigned short*)w; w += (size_t)MPAD * CC * 2;
    unsigned short* wt1   = (unsigned short*)w; w += (size_t)3 * CC * CC * 2;
    unsigned short* wt2   = (unsigned short*)w; w += (size_t)CC * CC * 2;
    unsigned short* qkvbf = (unsigned short*)w; w += (size_t)MTOT * 3 * CC * 2;
    unsigned short* atbf  = (unsigned short*)w; w += (size_t)MPAD * CC * 2;
    float* rws    = (float*)w; w += (size_t)BB * HH * CC * 4;
    float* bconst = (float*)w; w += (size_t)BB * HH * 4;
    float* sws    = (float*)w; w += (size_t)BB * HH * NTOK * 4;

    convert_x<<<dim3(4728), 256, 0, stream>>>(x, xbf);
    transpose_w<<<dim3(24, 72), 256, 0, stream>>>(qkv_w, wt1, 3 * CC);
    transpose_w<<<dim3(24, 24), 256, 0, stream>>>(proj_w, wt2, CC);
    gemm_bf16<<<dim3(8 * 18 * 13), 256, 0, stream>>>(xbf, wt1, qkv_b, 18, 0, qkvbf, nullptr);
    attn_mfma<<<dim3(BB * HH), 256, 0, stream>>>(qkvbf, atbf);
    gemm_bf16<<<dim3(8 * 6 * 13), 256, 0, stream>>>(atbf, wt2, proj_b, 6, 1,
                                                    nullptr, out + XOUT_OFF);
    qr_kernel<<<dim3(BB * HH), 256, 0, stream>>>(x, qkv_w, qkv_b, rws, bconst);
    cls_s<<<dim3(BB * HH), 256, 0, stream>>>(x, rws, bconst, sws);
    cls_topk<<<dim3(BB), 256, 0, stream>>>(sws, out, (out_size > LT_OFF) ? 1 : 0);
}